// Round 4
// baseline (543.122 us; speedup 1.0000x reference)
//
#include <hip/hip_runtime.h>
#include <hip/hip_bf16.h>

typedef __hip_bfloat16 bf16;
typedef unsigned short u16;
typedef unsigned int u32;
typedef __attribute__((ext_vector_type(8))) short short8;   // 8 x bf16 (4 VGPRs)
typedef __attribute__((ext_vector_type(4))) float floatx4;  // 4 x f32 acc

#define NROWS (8*128*128)   // 131072 spatial positions
#define DIM 256
#define QKVN 768
#define HD 32
#define SEQ 256             // stripe sequence length = sw(2) * 128

__device__ __forceinline__ float b2f_bits(u16 u) {
    union { float f; u32 i; } x; x.i = ((u32)u) << 16; return x.f;
}
__device__ __forceinline__ u16 f2b_bits(float f) {
    bf16 h = __float2bfloat16(f);
    return *reinterpret_cast<u16*>(&h);
}
__device__ __forceinline__ u32 pack2(float a, float b) {
    return ((u32)f2b_bits(b) << 16) | (u32)f2b_bits(a);
}
// load 8 consecutive bf16 (16B) -> 8 floats
__device__ __forceinline__ void load8f(const bf16* p, float* d) {
    uint4 w = *reinterpret_cast<const uint4*>(p);
    d[0] = b2f_bits((u16)(w.x & 0xffff)); d[1] = b2f_bits((u16)(w.x >> 16));
    d[2] = b2f_bits((u16)(w.y & 0xffff)); d[3] = b2f_bits((u16)(w.y >> 16));
    d[4] = b2f_bits((u16)(w.z & 0xffff)); d[5] = b2f_bits((u16)(w.z >> 16));
    d[6] = b2f_bits((u16)(w.w & 0xffff)); d[7] = b2f_bits((u16)(w.w >> 16));
}
// async global->LDS, 16B per lane (lds dest must be wave-uniform base + lane*16)
__device__ __forceinline__ void gload16(const void* g, void* l) {
    __builtin_amdgcn_global_load_lds(
        (const __attribute__((address_space(1))) void*)g,
        (__attribute__((address_space(3))) void*)l, 16, 0, 0);
}

// ---------------- Weight transpose+convert: W[k][n] f32 -> WT[n][k] bf16 ----
__global__ __launch_bounds__(256) void convert_kernel(
        const float* __restrict__ Wqkv, const float* __restrict__ Wproj,
        bf16* __restrict__ WTq, bf16* __restrict__ WTp) {
    const int n = blockIdx.x;
    const int k = threadIdx.x;
    if (n < QKVN) {
        WTq[(size_t)n * DIM + k] = __float2bfloat16(Wqkv[(size_t)k * QKVN + n]);
    } else {
        const int n2 = n - QKVN;
        WTp[(size_t)n2 * DIM + k] = __float2bfloat16(Wproj[(size_t)k * DIM + n2]);
    }
}

// ---------------- LayerNorm: one WAVE per row, float4 per lane -------------
// 64 lanes x float4 = 256 elems = one row. No LDS, no barriers: 6-step
// __shfl_xor reductions. Grid-stride over rows (16 rows/wave at 2048 blocks)
// so loads from successive rows overlap (MLP), gamma/beta hoisted to regs.
__global__ __launch_bounds__(256) void ln_kernel(
        const float* __restrict__ x, const float* __restrict__ gamma,
        const float* __restrict__ beta, bf16* __restrict__ xn,
        size_t x_off, int nrows) {
    const int t = threadIdx.x;
    const int wv = t >> 6, lane = t & 63;
    const int nwaves = gridDim.x << 2;
    const int wid = (blockIdx.x << 2) + wv;

    const float4 g4 = *reinterpret_cast<const float4*>(gamma + lane * 4);
    const float4 b4 = *reinterpret_cast<const float4*>(beta + lane * 4);

    for (int row = wid; row < nrows; row += nwaves) {
        const float4 v = *reinterpret_cast<const float4*>(
            x + x_off + (size_t)row * DIM + lane * 4);

        float s = v.x + v.y + v.z + v.w;
        #pragma unroll
        for (int off = 32; off > 0; off >>= 1) s += __shfl_xor(s, off, 64);
        const float mean = s * (1.0f / DIM);

        const float dx = v.x - mean, dy = v.y - mean;
        const float dz = v.z - mean, dw = v.w - mean;
        float s2 = dx * dx + dy * dy + dz * dz + dw * dw;
        #pragma unroll
        for (int off = 32; off > 0; off >>= 1) s2 += __shfl_xor(s2, off, 64);
        const float rstd = rsqrtf(s2 * (1.0f / DIM) + 1e-5f);

        uint2 o;
        o.x = pack2(dx * rstd * g4.x + b4.x, dy * rstd * g4.y + b4.y);
        o.y = pack2(dz * rstd * g4.z + b4.z, dw * rstd * g4.w + b4.w);
        *reinterpret_cast<uint2*>(xn + (size_t)row * DIM + lane * 4) = o;
    }
}

// ---------------- MFMA GEMM: C[M,N] = A[M,256] @ WT^T + bias (+resid) ------
// A: bf16 row-major [M][256]. WT: bf16 [N][256] (i.e. W transposed).
// 128x128 tile, BK=32, 4 waves in 2x2, each wave 4x4 mfma_f32_16x16x32_bf16.
// OUT_F32: f32 store + resid (final proj), direct stores (64B segments, fine).
// OUT_F32==0 (qkv): SWAPPED mfma operands -> lane owns 4 consecutive N-cols
// of one M-row; stage per-wave 64x64 bf16 tile in LDS (XOR-swizzled cols),
// read back 16B/lane -> 128B-contiguous global stores (fixes 2x write ampl).
// Both paths: XCD-chunked block swizzle so blocks sharing an A-panel land on
// the same XCD L2 (fixes A re-fetch amplification).
template<int OUT_F32>
__global__ __launch_bounds__(256) void gemm_mfma(
        const bf16* __restrict__ A, const bf16* __restrict__ WT,
        const float* __restrict__ bias, const float* __restrict__ resid,
        void* __restrict__ Cout, int N) {
    __shared__ __align__(16) bf16 As[128][32];   // 8 KiB
    __shared__ __align__(16) bf16 Bs[128][32];   // 8 KiB

    const int tid = threadIdx.x;
    const int lane = tid & 63, wave = tid >> 6;
    const int wm = (wave >> 1) * 64, wn = (wave & 1) * 64;
    const int m = lane & 15, quad = lane >> 4;

    // XCD-chunked swizzle (nwg % 8 == 0 for both grids used)
    const int nwg = gridDim.x * gridDim.y;
    const int L = blockIdx.y * gridDim.x + blockIdx.x;
    const int tile = (L & 7) * (nwg >> 3) + (L >> 3);
    const int bx = tile % gridDim.x, by = tile / gridDim.x;
    const int row0 = by * 128, col0 = bx * 128;

    floatx4 acc[4][4] = {};

    // staging chunk ids: c covers 16B = 8 elems; row = c>>2, koff = (c&3)*8
    const int c0 = tid, c1 = tid + 256;
    const int r0_ = c0 >> 2, o0 = (c0 & 3) * 8;
    const int r1_ = c1 >> 2, o1 = (c1 & 3) * 8;

    for (int k0 = 0; k0 < DIM; k0 += 32) {
        __syncthreads();
        gload16(A  + (size_t)(row0 + r0_) * DIM + k0 + o0, (bf16*)As + c0 * 8);
        gload16(A  + (size_t)(row0 + r1_) * DIM + k0 + o1, (bf16*)As + c1 * 8);
        gload16(WT + (size_t)(col0 + r0_) * DIM + k0 + o0, (bf16*)Bs + c0 * 8);
        gload16(WT + (size_t)(col0 + r1_) * DIM + k0 + o1, (bf16*)Bs + c1 * 8);
        __syncthreads();

        short8 af[4], bfr[4];
        #pragma unroll
        for (int i = 0; i < 4; i++)
            af[i] = *reinterpret_cast<const short8*>(&As[wm + i * 16 + m][quad * 8]);
        #pragma unroll
        for (int j = 0; j < 4; j++)
            bfr[j] = *reinterpret_cast<const short8*>(&Bs[wn + j * 16 + m][quad * 8]);
        #pragma unroll
        for (int i = 0; i < 4; i++) {
            #pragma unroll
            for (int j = 0; j < 4; j++) {
                if constexpr (OUT_F32) {
                    acc[i][j] = __builtin_amdgcn_mfma_f32_16x16x32_bf16(
                        af[i], bfr[j], acc[i][j], 0, 0, 0);
                } else {
                    // swapped: D^T -> col(lane&15)=M-row, row(quad*4+r)=N-col
                    acc[i][j] = __builtin_amdgcn_mfma_f32_16x16x32_bf16(
                        bfr[j], af[i], acc[i][j], 0, 0, 0);
                }
            }
        }
    }

    if constexpr (OUT_F32) {
        // C/D layout col = lane&15 (N), row = quad*4 + reg (M) (m89-verified)
        #pragma unroll
        for (int j = 0; j < 4; j++) {
            const int col = col0 + wn + j * 16 + m;
            const float bj = bias[col];
            #pragma unroll
            for (int i = 0; i < 4; i++) {
                #pragma unroll
                for (int r = 0; r < 4; r++) {
                    const int row = row0 + wm + i * 16 + quad * 4 + r;
                    ((float*)Cout)[(size_t)row * N + col] =
                        acc[i][j][r] + bj + resid[(size_t)row * N + col];
                }
            }
        }
    } else {
        // swapped layout: lane holds M-row (i*16+m), N-cols j*16+quad*4..+3
        __shared__ __align__(16) u16 Cs[4][64][64];   // 32 KiB, per-wave tile
        #pragma unroll
        for (int i = 0; i < 4; i++) {
            const int rr = i * 16 + m;
            const int sx = (m & 7) << 3;    // XOR swizzle (bits 3-5 of col)
            #pragma unroll
            for (int j = 0; j < 4; j++) {
                const int cc = j * 16 + quad * 4;
                const float4 bj = *reinterpret_cast<const float4*>(
                    &bias[col0 + wn + cc]);
                u32* p = reinterpret_cast<u32*>(&Cs[wave][rr][cc ^ sx]);
                p[0] = pack2(acc[i][j][0] + bj.x, acc[i][j][1] + bj.y);
                p[1] = pack2(acc[i][j][2] + bj.z, acc[i][j][3] + bj.w);
            }
        }
        // per-wave region, same-wave RAW -> no barrier needed
        #pragma unroll
        for (int p = 0; p < 8; p++) {
            const int rr = p * 8 + (lane >> 3);
            const int cc = (lane & 7) * 8;
            const uint4 v = *reinterpret_cast<const uint4*>(
                &Cs[wave][rr][cc ^ ((rr & 7) << 3)]);
            *reinterpret_cast<uint4*>(
                &((bf16*)Cout)[(size_t)(row0 + wm + rr) * N + col0 + wn + cc]) = v;
        }
    }
}

// ---------------- Stripe attention, MFMA version ----------------
// grid = dim3(512, nb): x = dir(2) x stripe(64) x head(4); y = batch image.
// Block: 256 thr = 4 waves; wave w owns query rows [w*64, w*64+64).
// SWAPPED QK^T: s = mfma(kf, qf) -> lane holds 4 CONSECUTIVE keys per reg
// block for q-row i*16+m -> P store is 2 x ds_write_b64 (not 32 x b16).
// Ps is per-wave and same-wave DS ops are in-order -> NO barriers in the
// chunk loop (waves free-run; MFMA of one wave overlaps exp of another).
__global__ __launch_bounds__(256) void attn_kernel(
        const bf16* __restrict__ qkv, bf16* __restrict__ h) {
    __shared__ __align__(16) u16 Ks[SEQ][HD];       // 16 KiB, linear (gload16)
    __shared__ __align__(16) u16 Vt[HD][264];       // 16.5 KiB, transposed+padded
    __shared__ __align__(16) u16 Ps[4][64][40];     // 20 KiB, per-wave P chunk

    const int bid = blockIdx.x;
    const int head = bid & 3;
    const int s = (bid >> 2) & 63;
    const int dir = bid >> 8;
    const int b = blockIdx.y;

    const int t = threadIdx.x;
    const int w = t >> 6, lane = t & 63;
    const int m = lane & 15, quad = lane >> 4;
    const int qoff = dir * 128 + head * HD;

    // spatial row of stripe-local index idx (0..255)
    auto row_of = [&](int idx) -> size_t {
        const int al = idx >> 7, l = idx & 127;
        int hp, wp;
        if (dir == 0) { hp = 2 * s + al; wp = l; }
        else          { wp = 2 * s + al; hp = l; }
        return ((size_t)(b * 128 + hp)) * 128 + wp;
    };

    // --- stage K linearly into LDS: 4 x 16B per thread (per-lane global src) ---
    #pragma unroll
    for (int j = 0; j < 4; j++) {
        const int e = t * 8 + j * 2048;      // flat element offset into Ks
        const int key = e >> 5;
        const int ko = e & 31;
        gload16(qkv + row_of(key) * QKVN + 256 + qoff + ko, (u16*)Ks + e);
    }

    // --- stage V transposed: thread t loads V row t, scatters Vt[d][t] ---
    {
        const bf16* vp = qkv + row_of(t) * QKVN + 512 + qoff;
        const uint4 v0 = *reinterpret_cast<const uint4*>(vp);
        const uint4 v1 = *reinterpret_cast<const uint4*>(vp + 8);
        const uint4 v2 = *reinterpret_cast<const uint4*>(vp + 16);
        const uint4 v3 = *reinterpret_cast<const uint4*>(vp + 24);
        const u32 ww[16] = { v0.x, v0.y, v0.z, v0.w, v1.x, v1.y, v1.z, v1.w,
                             v2.x, v2.y, v2.z, v2.w, v3.x, v3.y, v3.z, v3.w };
        #pragma unroll
        for (int d = 0; d < 16; d++) {
            Vt[2 * d][t]     = (u16)(ww[d] & 0xffff);
            Vt[2 * d + 1][t] = (u16)(ww[d] >> 16);
        }
    }

    // --- Q fragments in registers: rows w*64 + i*16 + m, k = quad*8 ---
    short8 qf[4];
    #pragma unroll
    for (int i = 0; i < 4; i++)
        qf[i] = *reinterpret_cast<const short8*>(
            qkv + row_of(w * 64 + i * 16 + m) * QKVN + qoff + quad * 8);

    __syncthreads();   // staging visible (also drains vmcnt for gload16)

    const float C = 0.25503494f;   // (1/sqrt(32)) * log2(e): p = exp2(s*C)
    floatx4 acc[4][2] = {};
    float rsl[4] = {};

    for (int c = 0; c < 8; c++) {
        // K fragments for this 32-key chunk (A-operand rows = key index)
        const short8 kf0 = *reinterpret_cast<const short8*>(&Ks[c * 32 + m][quad * 8]);
        const short8 kf1 = *reinterpret_cast<const short8*>(&Ks[c * 32 + 16 + m][quad * 8]);

        // QK^T (swapped): s0[r] = score[key=c*32+quad*4+r][q=i*16+m]
        #pragma unroll
        for (int i = 0; i < 4; i++) {
            const floatx4 z = {};
            floatx4 s0 = __builtin_amdgcn_mfma_f32_16x16x32_bf16(kf0, qf[i], z, 0, 0, 0);
            floatx4 s1 = __builtin_amdgcn_mfma_f32_16x16x32_bf16(kf1, qf[i], z, 0, 0, 0);
            float p0[4], p1[4];
            #pragma unroll
            for (int r = 0; r < 4; r++) {
                p0[r] = exp2f(s0[r] * C);
                p1[r] = exp2f(s1[r] * C);
                rsl[i] += p0[r] + p1[r];
            }
            // keys are consecutive per lane -> two 8B packed LDS writes
            uint2 wa, wb;
            wa.x = pack2(p0[0], p0[1]); wa.y = pack2(p0[2], p0[3]);
            wb.x = pack2(p1[0], p1[1]); wb.y = pack2(p1[2], p1[3]);
            *reinterpret_cast<uint2*>(&Ps[w][i * 16 + m][4 * quad])      = wa;
            *reinterpret_cast<uint2*>(&Ps[w][i * 16 + m][16 + 4 * quad]) = wb;
        }

        // V fragments: B[n=hd][k=key] = Vt[hd][key], contiguous in k
        const short8 vf0 = *reinterpret_cast<const short8*>(&Vt[m][c * 32 + quad * 8]);
        const short8 vf1 = *reinterpret_cast<const short8*>(&Vt[16 + m][c * 32 + quad * 8]);

        // PV: same-wave in-order DS guarantees Ps writes land before reads
        #pragma unroll
        for (int i = 0; i < 4; i++) {
            const short8 pf = *reinterpret_cast<const short8*>(&Ps[w][i * 16 + m][quad * 8]);
            __builtin_amdgcn_s_setprio(1);
            acc[i][0] = __builtin_amdgcn_mfma_f32_16x16x32_bf16(pf, vf0, acc[i][0], 0, 0, 0);
            acc[i][1] = __builtin_amdgcn_mfma_f32_16x16x32_bf16(pf, vf1, acc[i][1], 0, 0, 0);
            __builtin_amdgcn_s_setprio(0);
        }
    }

    // --- row-sums: local 8 keys/lane summed in rsl; reduce across quads ---
    #pragma unroll
    for (int i = 0; i < 4; i++) {
        float v = rsl[i];
        v += __shfl_xor(v, 16, 64);
        v += __shfl_xor(v, 32, 64);
        // v = full rowsum for q = i*16 + m (all quads agree)
        #pragma unroll
        for (int r = 0; r < 4; r++) {
            const float rv = __shfl(v, quad * 4 + r, 64);  // rowsum for this out row
            const float inv = 1.0f / rv;
            bf16* op = h + row_of(w * 64 + i * 16 + quad * 4 + r) * DIM + qoff;
            op[m]      = __float2bfloat16(acc[i][0][r] * inv);
            op[16 + m] = __float2bfloat16(acc[i][1][r] * inv);
        }
    }
}

extern "C" void kernel_launch(void* const* d_in, const int* in_sizes, int n_in,
                              void* d_out, int out_size, void* d_ws, size_t ws_size,
                              hipStream_t stream) {
    const float* x     = (const float*)d_in[0];
    const float* Wqkv  = (const float*)d_in[1];
    const float* bqkv  = (const float*)d_in[2];
    const float* Wproj = (const float*)d_in[3];
    const float* bproj = (const float*)d_in[4];
    const float* gamma = (const float*)d_in[5];
    const float* beta  = (const float*)d_in[6];
    char* ws = (char*)d_ws;

    const size_t MB256 = (size_t)268435456;
    if (ws_size >= MB256 + 524288) {
        // [0,64M): xn, later h   [64M,256M): qkv   [256M,+512K): WTq|WTp
        bf16* xn_h = (bf16*)ws;
        bf16* qkv  = (bf16*)(ws + (size_t)NROWS * DIM * 2);
        bf16* WTq  = (bf16*)(ws + MB256);
        bf16* WTp  = WTq + (size_t)QKVN * DIM;

        convert_kernel<<<QKVN + DIM, 256, 0, stream>>>(Wqkv, Wproj, WTq, WTp);
        ln_kernel<<<2048, 256, 0, stream>>>(x, gamma, beta, xn_h, 0, NROWS);
        gemm_mfma<0><<<dim3(QKVN / 128, NROWS / 128), 256, 0, stream>>>(
            xn_h, WTq, bqkv, nullptr, qkv, QKVN);
        attn_kernel<<<dim3(512, 8), 256, 0, stream>>>(qkv, xn_h);
        gemm_mfma<1><<<dim3(DIM / 128, NROWS / 128), 256, 0, stream>>>(
            xn_h, WTp, bproj, x, d_out, DIM);
    } else {
        // Per-image path: WT @0 (512K), xn_b @1M (8M), qkv_b @9M (24M), h_b @33M (8M)
        const int MB = NROWS / 8;   // 16384 rows per image
        bf16* WTq   = (bf16*)ws;
        bf16* WTp   = WTq + (size_t)QKVN * DIM;
        bf16* xn_b  = (bf16*)(ws + (size_t)1048576);
        bf16* qkv_b = (bf16*)(ws + (size_t)9 * 1048576);
        bf16* h_b   = (bf16*)(ws + (size_t)33 * 1048576);

        convert_kernel<<<QKVN + DIM, 256, 0, stream>>>(Wqkv, Wproj, WTq, WTp);
        for (int b = 0; b < 8; b++) {
            const size_t ro = (size_t)b * MB * DIM;
            ln_kernel<<<2048, 256, 0, stream>>>(x, gamma, beta, xn_b, ro, MB);
            gemm_mfma<0><<<dim3(QKVN / 128, MB / 128), 256, 0, stream>>>(
                xn_b, WTq, bqkv, nullptr, qkv_b, QKVN);
            attn_kernel<<<dim3(512, 1), 256, 0, stream>>>(qkv_b, h_b);
            gemm_mfma<1><<<dim3(DIM / 128, MB / 128), 256, 0, stream>>>(
                h_b, WTp, bproj, x + ro, (float*)d_out + ro, DIM);
        }
    }
}

// Round 5
// 531.190 us; speedup vs baseline: 1.0225x; 1.0225x over previous
//
#include <hip/hip_runtime.h>
#include <hip/hip_bf16.h>

typedef __hip_bfloat16 bf16;
typedef unsigned short u16;
typedef unsigned int u32;
typedef __attribute__((ext_vector_type(8))) short short8;   // 8 x bf16 (4 VGPRs)
typedef __attribute__((ext_vector_type(4))) float floatx4;  // 4 x f32 acc

#define NROWS (8*128*128)   // 131072 spatial positions
#define DIM 256
#define QKVN 768
#define HD 32
#define SEQ 256             // stripe sequence length = sw(2) * 128

__device__ __forceinline__ float b2f_bits(u16 u) {
    union { float f; u32 i; } x; x.i = ((u32)u) << 16; return x.f;
}
__device__ __forceinline__ u16 f2b_bits(float f) {
    bf16 h = __float2bfloat16(f);
    return *reinterpret_cast<u16*>(&h);
}
__device__ __forceinline__ u32 pack2(float a, float b) {
    return ((u32)f2b_bits(b) << 16) | (u32)f2b_bits(a);
}
// load 8 consecutive bf16 (16B) -> 8 floats
__device__ __forceinline__ void load8f(const bf16* p, float* d) {
    uint4 w = *reinterpret_cast<const uint4*>(p);
    d[0] = b2f_bits((u16)(w.x & 0xffff)); d[1] = b2f_bits((u16)(w.x >> 16));
    d[2] = b2f_bits((u16)(w.y & 0xffff)); d[3] = b2f_bits((u16)(w.y >> 16));
    d[4] = b2f_bits((u16)(w.z & 0xffff)); d[5] = b2f_bits((u16)(w.z >> 16));
    d[6] = b2f_bits((u16)(w.w & 0xffff)); d[7] = b2f_bits((u16)(w.w >> 16));
}
// async global->LDS, 16B per lane (lds dest must be wave-uniform base + lane*16)
__device__ __forceinline__ void gload16(const void* g, void* l) {
    __builtin_amdgcn_global_load_lds(
        (const __attribute__((address_space(1))) void*)g,
        (__attribute__((address_space(3))) void*)l, 16, 0, 0);
}

// ---------------- Weight transpose+convert: W[k][n] f32 -> WT[n][k] bf16 ----
__global__ __launch_bounds__(256) void convert_kernel(
        const float* __restrict__ Wqkv, const float* __restrict__ Wproj,
        bf16* __restrict__ WTq, bf16* __restrict__ WTp) {
    const int n = blockIdx.x;
    const int k = threadIdx.x;
    if (n < QKVN) {
        WTq[(size_t)n * DIM + k] = __float2bfloat16(Wqkv[(size_t)k * QKVN + n]);
    } else {
        const int n2 = n - QKVN;
        WTp[(size_t)n2 * DIM + k] = __float2bfloat16(Wproj[(size_t)k * DIM + n2]);
    }
}

// ---------------- LayerNorm: one WAVE per row, float4 per lane -------------
// 64 lanes x float4 = 256 elems = one row. No LDS, no barriers: 6-step
// __shfl_xor reductions. Grid-stride over rows (16 rows/wave at 2048 blocks)
// so loads from successive rows overlap (MLP), gamma/beta hoisted to regs.
__global__ __launch_bounds__(256) void ln_kernel(
        const float* __restrict__ x, const float* __restrict__ gamma,
        const float* __restrict__ beta, bf16* __restrict__ xn,
        size_t x_off, int nrows) {
    const int t = threadIdx.x;
    const int wv = t >> 6, lane = t & 63;
    const int nwaves = gridDim.x << 2;
    const int wid = (blockIdx.x << 2) + wv;

    const float4 g4 = *reinterpret_cast<const float4*>(gamma + lane * 4);
    const float4 b4 = *reinterpret_cast<const float4*>(beta + lane * 4);

    for (int row = wid; row < nrows; row += nwaves) {
        const float4 v = *reinterpret_cast<const float4*>(
            x + x_off + (size_t)row * DIM + lane * 4);

        float s = v.x + v.y + v.z + v.w;
        #pragma unroll
        for (int off = 32; off > 0; off >>= 1) s += __shfl_xor(s, off, 64);
        const float mean = s * (1.0f / DIM);

        const float dx = v.x - mean, dy = v.y - mean;
        const float dz = v.z - mean, dw = v.w - mean;
        float s2 = dx * dx + dy * dy + dz * dz + dw * dw;
        #pragma unroll
        for (int off = 32; off > 0; off >>= 1) s2 += __shfl_xor(s2, off, 64);
        const float rstd = rsqrtf(s2 * (1.0f / DIM) + 1e-5f);

        uint2 o;
        o.x = pack2(dx * rstd * g4.x + b4.x, dy * rstd * g4.y + b4.y);
        o.y = pack2(dz * rstd * g4.z + b4.z, dw * rstd * g4.w + b4.w);
        *reinterpret_cast<uint2*>(xn + (size_t)row * DIM + lane * 4) = o;
    }
}

// ---------------- MFMA GEMM: C[M,N] = A[M,256] @ WT^T + bias (+resid) ------
// A: bf16 row-major [M][256]. WT: bf16 [N][256] (i.e. W transposed).
// 128x128 tile, BK=32, 4 waves in 2x2, each wave 4x4 mfma_f32_16x16x32_bf16.
// OUT_F32: f32 store + resid (final proj), direct stores (64B segments, fine).
// OUT_F32==0 (qkv): SWAPPED mfma operands -> lane owns 4 consecutive N-cols
// of one M-row; stage per-wave 64x64 bf16 tile in LDS (XOR-swizzled cols),
// read back 16B/lane -> 128B-contiguous global stores (fixes 2x write ampl).
// Both paths: XCD-chunked block swizzle so blocks sharing an A-panel land on
// the same XCD L2 (fixes A re-fetch amplification).
template<int OUT_F32>
__global__ __launch_bounds__(256) void gemm_mfma(
        const bf16* __restrict__ A, const bf16* __restrict__ WT,
        const float* __restrict__ bias, const float* __restrict__ resid,
        void* __restrict__ Cout, int N) {
    __shared__ __align__(16) bf16 As[128][32];   // 8 KiB
    __shared__ __align__(16) bf16 Bs[128][32];   // 8 KiB

    const int tid = threadIdx.x;
    const int lane = tid & 63, wave = tid >> 6;
    const int wm = (wave >> 1) * 64, wn = (wave & 1) * 64;
    const int m = lane & 15, quad = lane >> 4;

    // XCD-chunked swizzle (nwg % 8 == 0 for both grids used)
    const int nwg = gridDim.x * gridDim.y;
    const int L = blockIdx.y * gridDim.x + blockIdx.x;
    const int tile = (L & 7) * (nwg >> 3) + (L >> 3);
    const int bx = tile % gridDim.x, by = tile / gridDim.x;
    const int row0 = by * 128, col0 = bx * 128;

    floatx4 acc[4][4] = {};

    // staging chunk ids: c covers 16B = 8 elems; row = c>>2, koff = (c&3)*8
    const int c0 = tid, c1 = tid + 256;
    const int r0_ = c0 >> 2, o0 = (c0 & 3) * 8;
    const int r1_ = c1 >> 2, o1 = (c1 & 3) * 8;

    for (int k0 = 0; k0 < DIM; k0 += 32) {
        __syncthreads();
        gload16(A  + (size_t)(row0 + r0_) * DIM + k0 + o0, (bf16*)As + c0 * 8);
        gload16(A  + (size_t)(row0 + r1_) * DIM + k0 + o1, (bf16*)As + c1 * 8);
        gload16(WT + (size_t)(col0 + r0_) * DIM + k0 + o0, (bf16*)Bs + c0 * 8);
        gload16(WT + (size_t)(col0 + r1_) * DIM + k0 + o1, (bf16*)Bs + c1 * 8);
        __syncthreads();

        short8 af[4], bfr[4];
        #pragma unroll
        for (int i = 0; i < 4; i++)
            af[i] = *reinterpret_cast<const short8*>(&As[wm + i * 16 + m][quad * 8]);
        #pragma unroll
        for (int j = 0; j < 4; j++)
            bfr[j] = *reinterpret_cast<const short8*>(&Bs[wn + j * 16 + m][quad * 8]);
        #pragma unroll
        for (int i = 0; i < 4; i++) {
            #pragma unroll
            for (int j = 0; j < 4; j++) {
                if constexpr (OUT_F32) {
                    acc[i][j] = __builtin_amdgcn_mfma_f32_16x16x32_bf16(
                        af[i], bfr[j], acc[i][j], 0, 0, 0);
                } else {
                    // swapped: D^T -> col(lane&15)=M-row, row(quad*4+r)=N-col
                    acc[i][j] = __builtin_amdgcn_mfma_f32_16x16x32_bf16(
                        bfr[j], af[i], acc[i][j], 0, 0, 0);
                }
            }
        }
    }

    if constexpr (OUT_F32) {
        // C/D layout col = lane&15 (N), row = quad*4 + reg (M) (m89-verified)
        #pragma unroll
        for (int j = 0; j < 4; j++) {
            const int col = col0 + wn + j * 16 + m;
            const float bj = bias[col];
            #pragma unroll
            for (int i = 0; i < 4; i++) {
                #pragma unroll
                for (int r = 0; r < 4; r++) {
                    const int row = row0 + wm + i * 16 + quad * 4 + r;
                    ((float*)Cout)[(size_t)row * N + col] =
                        acc[i][j][r] + bj + resid[(size_t)row * N + col];
                }
            }
        }
    } else {
        // swapped layout: lane holds M-row (i*16+m), N-cols j*16+quad*4..+3
        __shared__ __align__(16) u16 Cs[4][64][64];   // 32 KiB, per-wave tile
        #pragma unroll
        for (int i = 0; i < 4; i++) {
            const int rr = i * 16 + m;
            const int sx = (m & 7) << 3;    // XOR swizzle (bits 3-5 of col)
            #pragma unroll
            for (int j = 0; j < 4; j++) {
                const int cc = j * 16 + quad * 4;
                const float4 bj = *reinterpret_cast<const float4*>(
                    &bias[col0 + wn + cc]);
                u32* p = reinterpret_cast<u32*>(&Cs[wave][rr][cc ^ sx]);
                p[0] = pack2(acc[i][j][0] + bj.x, acc[i][j][1] + bj.y);
                p[1] = pack2(acc[i][j][2] + bj.z, acc[i][j][3] + bj.w);
            }
        }
        // per-wave region, same-wave RAW -> no barrier needed
        #pragma unroll
        for (int p = 0; p < 8; p++) {
            const int rr = p * 8 + (lane >> 3);
            const int cc = (lane & 7) * 8;
            const uint4 v = *reinterpret_cast<const uint4*>(
                &Cs[wave][rr][cc ^ ((rr & 7) << 3)]);
            *reinterpret_cast<uint4*>(
                &((bf16*)Cout)[(size_t)(row0 + wm + rr) * N + col0 + wn + cc]) = v;
        }
    }
}

// ---------------- Stripe attention, MFMA version ----------------
// grid = dim3(512, nb): x = dir(2) x stripe(64) x head(4); y = batch image.
// Block: 256 thr = 4 waves; wave w owns query rows [w*64, w*64+64).
// Round-3 proven structure (mfma(qf,kf), scalar b16 Ps stores) with two
// deltas: (a) NO per-chunk barriers -- Ps is per-wave and same-wave DS ops
// are in-order (correctness proven in round 4); waves free-run so one
// wave's PV MFMAs overlap another's exp phase. (b) exp2f(s*C) -- one fewer
// VALU op per score than __expf(s*scale), identical math.
__global__ __launch_bounds__(256) void attn_kernel(
        const bf16* __restrict__ qkv, bf16* __restrict__ h) {
    __shared__ __align__(16) u16 Ks[SEQ][HD];       // 16 KiB, linear (gload16)
    __shared__ __align__(16) u16 Vt[HD][264];       // 16.5 KiB, transposed+padded
    __shared__ __align__(16) u16 Ps[4][64][40];     // 20 KiB, per-wave P chunk

    const int bid = blockIdx.x;
    const int head = bid & 3;
    const int s = (bid >> 2) & 63;
    const int dir = bid >> 8;
    const int b = blockIdx.y;

    const int t = threadIdx.x;
    const int w = t >> 6, lane = t & 63;
    const int m = lane & 15, quad = lane >> 4;
    const int qoff = dir * 128 + head * HD;

    // spatial row of stripe-local index idx (0..255)
    auto row_of = [&](int idx) -> size_t {
        const int al = idx >> 7, l = idx & 127;
        int hp, wp;
        if (dir == 0) { hp = 2 * s + al; wp = l; }
        else          { wp = 2 * s + al; hp = l; }
        return ((size_t)(b * 128 + hp)) * 128 + wp;
    };

    // --- stage K linearly into LDS: 4 x 16B per thread (per-lane global src) ---
    #pragma unroll
    for (int j = 0; j < 4; j++) {
        const int e = t * 8 + j * 2048;      // flat element offset into Ks
        const int key = e >> 5;
        const int ko = e & 31;
        gload16(qkv + row_of(key) * QKVN + 256 + qoff + ko, (u16*)Ks + e);
    }

    // --- stage V transposed: thread t loads V row t, scatters Vt[d][t] ---
    {
        const bf16* vp = qkv + row_of(t) * QKVN + 512 + qoff;
        const uint4 v0 = *reinterpret_cast<const uint4*>(vp);
        const uint4 v1 = *reinterpret_cast<const uint4*>(vp + 8);
        const uint4 v2 = *reinterpret_cast<const uint4*>(vp + 16);
        const uint4 v3 = *reinterpret_cast<const uint4*>(vp + 24);
        const u32 ww[16] = { v0.x, v0.y, v0.z, v0.w, v1.x, v1.y, v1.z, v1.w,
                             v2.x, v2.y, v2.z, v2.w, v3.x, v3.y, v3.z, v3.w };
        #pragma unroll
        for (int d = 0; d < 16; d++) {
            Vt[2 * d][t]     = (u16)(ww[d] & 0xffff);
            Vt[2 * d + 1][t] = (u16)(ww[d] >> 16);
        }
    }

    // --- Q fragments in registers: rows w*64 + i*16 + m, k = quad*8 ---
    short8 qf[4];
    #pragma unroll
    for (int i = 0; i < 4; i++)
        qf[i] = *reinterpret_cast<const short8*>(
            qkv + row_of(w * 64 + i * 16 + m) * QKVN + qoff + quad * 8);

    __syncthreads();   // staging visible cross-wave (also drains gload16 vmcnt)

    const float C = 0.25503494f;   // (1/sqrt(32)) * log2(e): p = exp2(s*C)
    floatx4 acc[4][2] = {};
    floatx4 rs[4] = {};

    for (int c = 0; c < 8; c++) {
        // K fragments for this 32-key chunk (B-frag rows = key index)
        const short8 kf0 = *reinterpret_cast<const short8*>(&Ks[c * 32 + m][quad * 8]);
        const short8 kf1 = *reinterpret_cast<const short8*>(&Ks[c * 32 + 16 + m][quad * 8]);

        #pragma unroll
        for (int i = 0; i < 4; i++) {
            const floatx4 z = {};
            floatx4 s0 = __builtin_amdgcn_mfma_f32_16x16x32_bf16(qf[i], kf0, z, 0, 0, 0);
            floatx4 s1 = __builtin_amdgcn_mfma_f32_16x16x32_bf16(qf[i], kf1, z, 0, 0, 0);
            #pragma unroll
            for (int r = 0; r < 4; r++) {
                const float p0 = exp2f(s0[r] * C);
                const float p1 = exp2f(s1[r] * C);
                rs[i][r] += p0 + p1;
                // C-layout -> Ps: row = i*16 + quad*4 + r, col = key-in-chunk
                Ps[w][i * 16 + quad * 4 + r][m]      = f2b_bits(p0);
                Ps[w][i * 16 + quad * 4 + r][16 + m] = f2b_bits(p1);
            }
        }
        // no barrier: Ps is per-wave; same-wave DS ops execute in order

        // V fragments: B[n=hd][k=key] = Vt[hd][key], contiguous in k
        const short8 vf0 = *reinterpret_cast<const short8*>(&Vt[m][c * 32 + quad * 8]);
        const short8 vf1 = *reinterpret_cast<const short8*>(&Vt[16 + m][c * 32 + quad * 8]);

        #pragma unroll
        for (int i = 0; i < 4; i++) {
            const short8 pf = *reinterpret_cast<const short8*>(&Ps[w][i * 16 + m][quad * 8]);
            acc[i][0] = __builtin_amdgcn_mfma_f32_16x16x32_bf16(pf, vf0, acc[i][0], 0, 0, 0);
            acc[i][1] = __builtin_amdgcn_mfma_f32_16x16x32_bf16(pf, vf1, acc[i][1], 0, 0, 0);
        }
        // no barrier: next chunk's Ps writes (same wave) stay ordered after reads
    }

    // --- row-sum reduce across the 16 lanes of each quad (xor 1,2,4,8) ---
    #pragma unroll
    for (int i = 0; i < 4; i++) {
        #pragma unroll
        for (int r = 0; r < 4; r++) {
            float v = rs[i][r];
            v += __shfl_xor(v, 1);
            v += __shfl_xor(v, 2);
            v += __shfl_xor(v, 4);
            v += __shfl_xor(v, 8);
            rs[i][r] = v;
        }
    }

    // --- epilogue: out[q][hd] = acc / lsum; col = h*16+m, row = quad*4+r ---
    #pragma unroll
    for (int i = 0; i < 4; i++) {
        #pragma unroll
        for (int r = 0; r < 4; r++) {
            const float inv = 1.0f / rs[i][r];
            bf16* op = h + row_of(w * 64 + i * 16 + quad * 4 + r) * DIM + qoff;
            op[m]      = __float2bfloat16(acc[i][0][r] * inv);
            op[16 + m] = __float2bfloat16(acc[i][1][r] * inv);
        }
    }
}

extern "C" void kernel_launch(void* const* d_in, const int* in_sizes, int n_in,
                              void* d_out, int out_size, void* d_ws, size_t ws_size,
                              hipStream_t stream) {
    const float* x     = (const float*)d_in[0];
    const float* Wqkv  = (const float*)d_in[1];
    const float* bqkv  = (const float*)d_in[2];
    const float* Wproj = (const float*)d_in[3];
    const float* bproj = (const float*)d_in[4];
    const float* gamma = (const float*)d_in[5];
    const float* beta  = (const float*)d_in[6];
    char* ws = (char*)d_ws;

    const size_t MB256 = (size_t)268435456;
    if (ws_size >= MB256 + 524288) {
        // [0,64M): xn, later h   [64M,256M): qkv   [256M,+512K): WTq|WTp
        bf16* xn_h = (bf16*)ws;
        bf16* qkv  = (bf16*)(ws + (size_t)NROWS * DIM * 2);
        bf16* WTq  = (bf16*)(ws + MB256);
        bf16* WTp  = WTq + (size_t)QKVN * DIM;

        convert_kernel<<<QKVN + DIM, 256, 0, stream>>>(Wqkv, Wproj, WTq, WTp);
        ln_kernel<<<2048, 256, 0, stream>>>(x, gamma, beta, xn_h, 0, NROWS);
        gemm_mfma<0><<<dim3(QKVN / 128, NROWS / 128), 256, 0, stream>>>(
            xn_h, WTq, bqkv, nullptr, qkv, QKVN);
        attn_kernel<<<dim3(512, 8), 256, 0, stream>>>(qkv, xn_h);
        gemm_mfma<1><<<dim3(DIM / 128, NROWS / 128), 256, 0, stream>>>(
            xn_h, WTp, bproj, x, d_out, DIM);
    } else {
        // Per-image path: WT @0 (512K), xn_b @1M (8M), qkv_b @9M (24M), h_b @33M (8M)
        const int MB = NROWS / 8;   // 16384 rows per image
        bf16* WTq   = (bf16*)ws;
        bf16* WTp   = WTq + (size_t)QKVN * DIM;
        bf16* xn_b  = (bf16*)(ws + (size_t)1048576);
        bf16* qkv_b = (bf16*)(ws + (size_t)9 * 1048576);
        bf16* h_b   = (bf16*)(ws + (size_t)33 * 1048576);

        convert_kernel<<<QKVN + DIM, 256, 0, stream>>>(Wqkv, Wproj, WTq, WTp);
        for (int b = 0; b < 8; b++) {
            const size_t ro = (size_t)b * MB * DIM;
            ln_kernel<<<2048, 256, 0, stream>>>(x, gamma, beta, xn_b, ro, MB);
            gemm_mfma<0><<<dim3(QKVN / 128, MB / 128), 256, 0, stream>>>(
                xn_b, WTq, bqkv, nullptr, qkv_b, QKVN);
            attn_kernel<<<dim3(512, 1), 256, 0, stream>>>(qkv_b, h_b);
            gemm_mfma<1><<<dim3(DIM / 128, MB / 128), 256, 0, stream>>>(
                h_b, WTp, bproj, x + ro, (float*)d_out + ro, DIM);
        }
    }
}

// Round 7
// 518.951 us; speedup vs baseline: 1.0466x; 1.0236x over previous
//
#include <hip/hip_runtime.h>
#include <hip/hip_bf16.h>

typedef __hip_bfloat16 bf16;
typedef unsigned short u16;
typedef unsigned int u32;
typedef __attribute__((ext_vector_type(8))) short short8;   // 8 x bf16 (4 VGPRs)
typedef __attribute__((ext_vector_type(4))) float floatx4;  // 4 x f32 acc

#define NROWS (8*128*128)   // 131072 spatial positions
#define DIM 256
#define QKVN 768
#define HD 32
#define SEQ 256             // stripe sequence length = sw(2) * 128
#define QSCALE 0.25503494f  // (1/sqrt(32)) * log2(e), folded into Wq/bq

__device__ __forceinline__ float b2f_bits(u16 u) {
    union { float f; u32 i; } x; x.i = ((u32)u) << 16; return x.f;
}
__device__ __forceinline__ u16 f2b_bits(float f) {
    bf16 h = __float2bfloat16(f);
    return *reinterpret_cast<u16*>(&h);
}
__device__ __forceinline__ u32 pack2(float a, float b) {
    return ((u32)f2b_bits(b) << 16) | (u32)f2b_bits(a);
}
// load 8 consecutive bf16 (16B) -> 8 floats
__device__ __forceinline__ void load8f(const bf16* p, float* d) {
    uint4 w = *reinterpret_cast<const uint4*>(p);
    d[0] = b2f_bits((u16)(w.x & 0xffff)); d[1] = b2f_bits((u16)(w.x >> 16));
    d[2] = b2f_bits((u16)(w.y & 0xffff)); d[3] = b2f_bits((u16)(w.y >> 16));
    d[4] = b2f_bits((u16)(w.z & 0xffff)); d[5] = b2f_bits((u16)(w.z >> 16));
    d[6] = b2f_bits((u16)(w.w & 0xffff)); d[7] = b2f_bits((u16)(w.w >> 16));
}
// async global->LDS, 16B per lane (lds dest must be wave-uniform base + lane*16)
__device__ __forceinline__ void gload16(const void* g, void* l) {
    __builtin_amdgcn_global_load_lds(
        (const __attribute__((address_space(1))) void*)g,
        (__attribute__((address_space(3))) void*)l, 16, 0, 0);
}

// ---------------- Weight transpose+convert: W[k][n] f32 -> WT[n][k] bf16 ----
// q-columns (n < DIM) of Wqkv are pre-scaled by QSCALE (f32, before bf16
// rounding) so attention computes p = exp2(s) with no per-score multiply.
__global__ __launch_bounds__(256) void convert_kernel(
        const float* __restrict__ Wqkv, const float* __restrict__ Wproj,
        bf16* __restrict__ WTq, bf16* __restrict__ WTp) {
    const int n = blockIdx.x;
    const int k = threadIdx.x;
    if (n < QKVN) {
        float v = Wqkv[(size_t)k * QKVN + n];
        if (n < DIM) v *= QSCALE;
        WTq[(size_t)n * DIM + k] = __float2bfloat16(v);
    } else {
        const int n2 = n - QKVN;
        WTp[(size_t)n2 * DIM + k] = __float2bfloat16(Wproj[(size_t)k * DIM + n2]);
    }
}

// ---------------- LayerNorm: one WAVE per row, float4 per lane -------------
// 64 lanes x float4 = 256 elems = one row. No LDS, no barriers: 6-step
// __shfl_xor reductions. Grid-stride over rows (16 rows/wave at 2048 blocks)
// so loads from successive rows overlap (MLP), gamma/beta hoisted to regs.
__global__ __launch_bounds__(256) void ln_kernel(
        const float* __restrict__ x, const float* __restrict__ gamma,
        const float* __restrict__ beta, bf16* __restrict__ xn,
        size_t x_off, int nrows) {
    const int t = threadIdx.x;
    const int wv = t >> 6, lane = t & 63;
    const int nwaves = gridDim.x << 2;
    const int wid = (blockIdx.x << 2) + wv;

    const float4 g4 = *reinterpret_cast<const float4*>(gamma + lane * 4);
    const float4 b4 = *reinterpret_cast<const float4*>(beta + lane * 4);

    for (int row = wid; row < nrows; row += nwaves) {
        const float4 v = *reinterpret_cast<const float4*>(
            x + x_off + (size_t)row * DIM + lane * 4);

        float s = v.x + v.y + v.z + v.w;
        #pragma unroll
        for (int off = 32; off > 0; off >>= 1) s += __shfl_xor(s, off, 64);
        const float mean = s * (1.0f / DIM);

        const float dx = v.x - mean, dy = v.y - mean;
        const float dz = v.z - mean, dw = v.w - mean;
        float s2 = dx * dx + dy * dy + dz * dz + dw * dw;
        #pragma unroll
        for (int off = 32; off > 0; off >>= 1) s2 += __shfl_xor(s2, off, 64);
        const float rstd = rsqrtf(s2 * (1.0f / DIM) + 1e-5f);

        uint2 o;
        o.x = pack2(dx * rstd * g4.x + b4.x, dy * rstd * g4.y + b4.y);
        o.y = pack2(dz * rstd * g4.z + b4.z, dw * rstd * g4.w + b4.w);
        *reinterpret_cast<uint2*>(xn + (size_t)row * DIM + lane * 4) = o;
    }
}

// ---------------- MFMA GEMM: C[M,N] = A[M,256] @ WT^T + bias (+resid) ------
// A: bf16 row-major [M][256]. WT: bf16 [N][256] (i.e. W transposed).
// 128x128 tile, BK=32, 4 waves in 2x2, each wave 4x4 mfma_f32_16x16x32_bf16.
// OUT_F32: f32 store + resid (final proj), direct stores (64B segments, fine).
// OUT_F32==0 (qkv): SWAPPED mfma operands -> lane owns 4 consecutive N-cols
// of one M-row; stage per-wave 64x64 bf16 tile in LDS (XOR-swizzled cols),
// read back 16B/lane -> 128B-contiguous global stores (fixes 2x write ampl).
// qkv path also scales bias cols < DIM by QSCALE (matches scaled Wq).
// Both paths: XCD-chunked block swizzle so blocks sharing an A-panel land on
// the same XCD L2 (fixes A re-fetch amplification).
template<int OUT_F32>
__global__ __launch_bounds__(256) void gemm_mfma(
        const bf16* __restrict__ A, const bf16* __restrict__ WT,
        const float* __restrict__ bias, const float* __restrict__ resid,
        void* __restrict__ Cout, int N) {
    __shared__ __align__(16) bf16 As[128][32];   // 8 KiB
    __shared__ __align__(16) bf16 Bs[128][32];   // 8 KiB

    const int tid = threadIdx.x;
    const int lane = tid & 63, wave = tid >> 6;
    const int wm = (wave >> 1) * 64, wn = (wave & 1) * 64;
    const int m = lane & 15, quad = lane >> 4;

    // XCD-chunked swizzle (nwg % 8 == 0 for both grids used)
    const int nwg = gridDim.x * gridDim.y;
    const int L = blockIdx.y * gridDim.x + blockIdx.x;
    const int tile = (L & 7) * (nwg >> 3) + (L >> 3);
    const int bx = tile % gridDim.x, by = tile / gridDim.x;
    const int row0 = by * 128, col0 = bx * 128;

    floatx4 acc[4][4] = {};

    // staging chunk ids: c covers 16B = 8 elems; row = c>>2, koff = (c&3)*8
    const int c0 = tid, c1 = tid + 256;
    const int r0_ = c0 >> 2, o0 = (c0 & 3) * 8;
    const int r1_ = c1 >> 2, o1 = (c1 & 3) * 8;

    for (int k0 = 0; k0 < DIM; k0 += 32) {
        __syncthreads();
        gload16(A  + (size_t)(row0 + r0_) * DIM + k0 + o0, (bf16*)As + c0 * 8);
        gload16(A  + (size_t)(row0 + r1_) * DIM + k0 + o1, (bf16*)As + c1 * 8);
        gload16(WT + (size_t)(col0 + r0_) * DIM + k0 + o0, (bf16*)Bs + c0 * 8);
        gload16(WT + (size_t)(col0 + r1_) * DIM + k0 + o1, (bf16*)Bs + c1 * 8);
        __syncthreads();

        short8 af[4], bfr[4];
        #pragma unroll
        for (int i = 0; i < 4; i++)
            af[i] = *reinterpret_cast<const short8*>(&As[wm + i * 16 + m][quad * 8]);
        #pragma unroll
        for (int j = 0; j < 4; j++)
            bfr[j] = *reinterpret_cast<const short8*>(&Bs[wn + j * 16 + m][quad * 8]);
        #pragma unroll
        for (int i = 0; i < 4; i++) {
            #pragma unroll
            for (int j = 0; j < 4; j++) {
                if constexpr (OUT_F32) {
                    acc[i][j] = __builtin_amdgcn_mfma_f32_16x16x32_bf16(
                        af[i], bfr[j], acc[i][j], 0, 0, 0);
                } else {
                    // swapped: D^T -> col(lane&15)=M-row, row(quad*4+r)=N-col
                    acc[i][j] = __builtin_amdgcn_mfma_f32_16x16x32_bf16(
                        bfr[j], af[i], acc[i][j], 0, 0, 0);
                }
            }
        }
    }

    if constexpr (OUT_F32) {
        // C/D layout col = lane&15 (N), row = quad*4 + reg (M) (m89-verified)
        #pragma unroll
        for (int j = 0; j < 4; j++) {
            const int col = col0 + wn + j * 16 + m;
            const float bj = bias[col];
            #pragma unroll
            for (int i = 0; i < 4; i++) {
                #pragma unroll
                for (int r = 0; r < 4; r++) {
                    const int row = row0 + wm + i * 16 + quad * 4 + r;
                    ((float*)Cout)[(size_t)row * N + col] =
                        acc[i][j][r] + bj + resid[(size_t)row * N + col];
                }
            }
        }
    } else {
        // swapped layout: lane holds M-row (i*16+m), N-cols j*16+quad*4..+3
        __shared__ __align__(16) u16 Cs[4][64][64];   // 32 KiB, per-wave tile
        #pragma unroll
        for (int i = 0; i < 4; i++) {
            const int rr = i * 16 + m;
            const int sx = (m & 7) << 3;    // XOR swizzle (bits 3-5 of col)
            #pragma unroll
            for (int j = 0; j < 4; j++) {
                const int cc = j * 16 + quad * 4;
                const int ccol = col0 + wn + cc;
                float4 bj = *reinterpret_cast<const float4*>(&bias[ccol]);
                if (ccol < DIM) {   // q-columns: bias scaled like Wq
                    bj.x *= QSCALE; bj.y *= QSCALE;
                    bj.z *= QSCALE; bj.w *= QSCALE;
                }
                u32* p = reinterpret_cast<u32*>(&Cs[wave][rr][cc ^ sx]);
                p[0] = pack2(acc[i][j][0] + bj.x, acc[i][j][1] + bj.y);
                p[1] = pack2(acc[i][j][2] + bj.z, acc[i][j][3] + bj.w);
            }
        }
        // per-wave region, same-wave RAW -> no barrier needed
        #pragma unroll
        for (int p = 0; p < 8; p++) {
            const int rr = p * 8 + (lane >> 3);
            const int cc = (lane & 7) * 8;
            const uint4 v = *reinterpret_cast<const uint4*>(
                &Cs[wave][rr][cc ^ ((rr & 7) << 3)]);
            *reinterpret_cast<uint4*>(
                &((bf16*)Cout)[(size_t)(row0 + wm + rr) * N + col0 + wn + cc]) = v;
        }
    }
}

// ---------------- Stripe attention, MFMA version ----------------
// grid = dim3(512, nb): x = dir(2) x stripe(64) x head(4); y = batch image.
// Block: 256 thr = 4 waves; wave w owns query rows [w*64, w*64+64).
// Round-3 proven structure (mfma(qf,kf), both per-chunk barriers -- lockstep
// measured FASTER than free-run, rounds 4/5). Deltas vs round 3:
//  (a) q pre-scaled by QSCALE in the qkv GEMM -> p = exp2f(s), no mul.
//  (b) chunk-local key PERMUTATION (key m -> slot 2m, key 16+m -> 2m+1) so
//      each lane's p0/p1 are adjacent -> ONE packed u32 store per r
//      (cvt_pk-fusable) instead of two ds_write_b16; V staged with the same
//      permutation so P.V is unchanged. Write banks: 2-way (free).
__global__ __launch_bounds__(256) void attn_kernel(
        const bf16* __restrict__ qkv, bf16* __restrict__ h) {
    __shared__ __align__(16) u16 Ks[SEQ][HD];       // 16 KiB, linear (gload16)
    __shared__ __align__(16) u16 Vt[HD][264];       // 16.5 KiB, transposed+padded
    __shared__ __align__(16) u16 Ps[4][64][40];     // 20 KiB, per-wave P chunk

    const int bid = blockIdx.x;
    const int head = bid & 3;
    const int s = (bid >> 2) & 63;
    const int dir = bid >> 8;
    const int b = blockIdx.y;

    const int t = threadIdx.x;
    const int w = t >> 6, lane = t & 63;
    const int m = lane & 15, quad = lane >> 4;
    const int qoff = dir * 128 + head * HD;

    // spatial row of stripe-local index idx (0..255)
    auto row_of = [&](int idx) -> size_t {
        const int al = idx >> 7, l = idx & 127;
        int hp, wp;
        if (dir == 0) { hp = 2 * s + al; wp = l; }
        else          { wp = 2 * s + al; hp = l; }
        return ((size_t)(b * 128 + hp)) * 128 + wp;
    };

    // --- stage K linearly into LDS: 4 x 16B per thread (per-lane global src) ---
    #pragma unroll
    for (int j = 0; j < 4; j++) {
        const int e = t * 8 + j * 2048;      // flat element offset into Ks
        const int key = e >> 5;
        const int ko = e & 31;
        gload16(qkv + row_of(key) * QKVN + 256 + qoff + ko, (u16*)Ks + e);
    }

    // --- stage V transposed + key-permuted: thread t (key t) scatters to
    //     column vcol = c*32 + ((kk&15)<<1 | kk>>4), matching P's slot order.
    {
        const int vcol = (t & 0xE0) | (((t & 15) << 1) | ((t >> 4) & 1));
        const bf16* vp = qkv + row_of(t) * QKVN + 512 + qoff;
        const uint4 v0 = *reinterpret_cast<const uint4*>(vp);
        const uint4 v1 = *reinterpret_cast<const uint4*>(vp + 8);
        const uint4 v2 = *reinterpret_cast<const uint4*>(vp + 16);
        const uint4 v3 = *reinterpret_cast<const uint4*>(vp + 24);
        const u32 ww[16] = { v0.x, v0.y, v0.z, v0.w, v1.x, v1.y, v1.z, v1.w,
                             v2.x, v2.y, v2.z, v2.w, v3.x, v3.y, v3.z, v3.w };
        #pragma unroll
        for (int d = 0; d < 16; d++) {
            Vt[2 * d][vcol]     = (u16)(ww[d] & 0xffff);
            Vt[2 * d + 1][vcol] = (u16)(ww[d] >> 16);
        }
    }

    // --- Q fragments in registers: rows w*64 + i*16 + m, k = quad*8 ---
    // (q is pre-scaled by QSCALE from the qkv GEMM)
    short8 qf[4];
    #pragma unroll
    for (int i = 0; i < 4; i++)
        qf[i] = *reinterpret_cast<const short8*>(
            qkv + row_of(w * 64 + i * 16 + m) * QKVN + qoff + quad * 8);

    __syncthreads();   // staging visible (also drains gload16 vmcnt)

    floatx4 acc[4][2] = {};
    floatx4 rs[4] = {};

    for (int c = 0; c < 8; c++) {
        // K fragments for this 32-key chunk (B-frag rows = key index)
        const short8 kf0 = *reinterpret_cast<const short8*>(&Ks[c * 32 + m][quad * 8]);
        const short8 kf1 = *reinterpret_cast<const short8*>(&Ks[c * 32 + 16 + m][quad * 8]);

        #pragma unroll
        for (int i = 0; i < 4; i++) {
            const floatx4 z = {};
            floatx4 s0 = __builtin_amdgcn_mfma_f32_16x16x32_bf16(qf[i], kf0, z, 0, 0, 0);
            floatx4 s1 = __builtin_amdgcn_mfma_f32_16x16x32_bf16(qf[i], kf1, z, 0, 0, 0);
            #pragma unroll
            for (int r = 0; r < 4; r++) {
                const float p0 = exp2f(s0[r]);     // pre-scaled q: no mul
                const float p1 = exp2f(s1[r]);
                rs[i][r] += p0 + p1;
                // C-layout row = i*16 + quad*4 + r; keys m & 16+m -> slots
                // 2m, 2m+1 (permuted): one packed u32 store.
                *reinterpret_cast<u32*>(
                    &Ps[w][i * 16 + quad * 4 + r][2 * m]) = pack2(p0, p1);
            }
        }
        __syncthreads();   // lockstep phases (measured faster than free-run)

        // V fragments: B[n=hd][slot] = Vt[hd][slot], slots match P's order
        const short8 vf0 = *reinterpret_cast<const short8*>(&Vt[m][c * 32 + quad * 8]);
        const short8 vf1 = *reinterpret_cast<const short8*>(&Vt[16 + m][c * 32 + quad * 8]);

        #pragma unroll
        for (int i = 0; i < 4; i++) {
            const short8 pf = *reinterpret_cast<const short8*>(&Ps[w][i * 16 + m][quad * 8]);
            acc[i][0] = __builtin_amdgcn_mfma_f32_16x16x32_bf16(pf, vf0, acc[i][0], 0, 0, 0);
            acc[i][1] = __builtin_amdgcn_mfma_f32_16x16x32_bf16(pf, vf1, acc[i][1], 0, 0, 0);
        }
        __syncthreads();   // Ps reads done before next chunk's writes (WAR)
    }

    // --- row-sum reduce across the 16 lanes of each quad (xor 1,2,4,8) ---
    #pragma unroll
    for (int i = 0; i < 4; i++) {
        #pragma unroll
        for (int r = 0; r < 4; r++) {
            float v = rs[i][r];
            v += __shfl_xor(v, 1);
            v += __shfl_xor(v, 2);
            v += __shfl_xor(v, 4);
            v += __shfl_xor(v, 8);
            rs[i][r] = v;
        }
    }

    // --- epilogue: out[q][hd] = acc / lsum; col = h*16+m, row = quad*4+r ---
    #pragma unroll
    for (int i = 0; i < 4; i++) {
        #pragma unroll
        for (int r = 0; r < 4; r++) {
            const float inv = 1.0f / rs[i][r];
            bf16* op = h + row_of(w * 64 + i * 16 + quad * 4 + r) * DIM + qoff;
            op[m]      = __float2bfloat16(acc[i][0][r] * inv);
            op[16 + m] = __float2bfloat16(acc[i][1][r] * inv);
        }
    }
}

extern "C" void kernel_launch(void* const* d_in, const int* in_sizes, int n_in,
                              void* d_out, int out_size, void* d_ws, size_t ws_size,
                              hipStream_t stream) {
    const float* x     = (const float*)d_in[0];
    const float* Wqkv  = (const float*)d_in[1];
    const float* bqkv  = (const float*)d_in[2];
    const float* Wproj = (const float*)d_in[3];
    const float* bproj = (const float*)d_in[4];
    const float* gamma = (const float*)d_in[5];
    const float* beta  = (const float*)d_in[6];
    char* ws = (char*)d_ws;

    const size_t MB256 = (size_t)268435456;
    if (ws_size >= MB256 + 524288) {
        // [0,64M): xn, later h   [64M,256M): qkv   [256M,+512K): WTq|WTp
        bf16* xn_h = (bf16*)ws;
        bf16* qkv  = (bf16*)(ws + (size_t)NROWS * DIM * 2);
        bf16* WTq  = (bf16*)(ws + MB256);
        bf16* WTp  = WTq + (size_t)QKVN * DIM;

        convert_kernel<<<QKVN + DIM, 256, 0, stream>>>(Wqkv, Wproj, WTq, WTp);
        ln_kernel<<<2048, 256, 0, stream>>>(x, gamma, beta, xn_h, 0, NROWS);
        gemm_mfma<0><<<dim3(QKVN / 128, NROWS / 128), 256, 0, stream>>>(
            xn_h, WTq, bqkv, nullptr, qkv, QKVN);
        attn_kernel<<<dim3(512, 8), 256, 0, stream>>>(qkv, xn_h);
        gemm_mfma<1><<<dim3(DIM / 128, NROWS / 128), 256, 0, stream>>>(
            xn_h, WTp, bproj, x, d_out, DIM);
    } else {
        // Per-image path: WT @0 (512K), xn_b @1M (8M), qkv_b @9M (24M), h_b @33M (8M)
        const int MB = NROWS / 8;   // 16384 rows per image
        bf16* WTq   = (bf16*)ws;
        bf16* WTp   = WTq + (size_t)QKVN * DIM;
        bf16* xn_b  = (bf16*)(ws + (size_t)1048576);
        bf16* qkv_b = (bf16*)(ws + (size_t)9 * 1048576);
        bf16* h_b   = (bf16*)(ws + (size_t)33 * 1048576);

        convert_kernel<<<QKVN + DIM, 256, 0, stream>>>(Wqkv, Wproj, WTq, WTp);
        for (int b = 0; b < 8; b++) {
            const size_t ro = (size_t)b * MB * DIM;
            ln_kernel<<<2048, 256, 0, stream>>>(x, gamma, beta, xn_b, ro, MB);
            gemm_mfma<0><<<dim3(QKVN / 128, MB / 128), 256, 0, stream>>>(
                xn_b, WTq, bqkv, nullptr, qkv_b, QKVN);
            attn_kernel<<<dim3(512, 1), 256, 0, stream>>>(qkv_b, h_b);
            gemm_mfma<1><<<dim3(DIM / 128, MB / 128), 256, 0, stream>>>(
                h_b, WTp, bproj, x + ro, (float*)d_out + ro, DIM);
        }
    }
}

// Round 8
// 491.161 us; speedup vs baseline: 1.1058x; 1.0566x over previous
//
#include <hip/hip_runtime.h>
#include <hip/hip_bf16.h>

typedef __hip_bfloat16 bf16;
typedef unsigned short u16;
typedef unsigned int u32;
typedef __attribute__((ext_vector_type(8))) short short8;   // 8 x bf16 (4 VGPRs)
typedef __attribute__((ext_vector_type(4))) float floatx4;  // 4 x f32 acc

#define NROWS (8*128*128)   // 131072 spatial positions
#define DIM 256
#define QKVN 768
#define HD 32
#define SEQ 256             // stripe sequence length = sw(2) * 128
#define QSCALE 0.25503494f  // (1/sqrt(32)) * log2(e), folded into Wq/bq

__device__ __forceinline__ float b2f_bits(u16 u) {
    union { float f; u32 i; } x; x.i = ((u32)u) << 16; return x.f;
}
__device__ __forceinline__ u16 f2b_bits(float f) {
    bf16 h = __float2bfloat16(f);
    return *reinterpret_cast<u16*>(&h);
}
__device__ __forceinline__ u32 pack2(float a, float b) {
    return ((u32)f2b_bits(b) << 16) | (u32)f2b_bits(a);
}
// native transcendental: D = 2^x (1 VALU op; exp2f libm path measured +40% VALU, r7)
__device__ __forceinline__ float fexp2(float x) {
    float r;
    asm("v_exp_f32 %0, %1" : "=v"(r) : "v"(x));
    return r;
}
// HW packed bf16 convert (RNE): lo16 = bf16(a), hi16 = bf16(b) (T12 primitive)
__device__ __forceinline__ u32 cvtpk(float a, float b) {
    u32 r;
    asm("v_cvt_pk_bf16_f32 %0, %1, %2" : "=v"(r) : "v"(a), "v"(b));
    return r;
}
// load 8 consecutive bf16 (16B) -> 8 floats
__device__ __forceinline__ void load8f(const bf16* p, float* d) {
    uint4 w = *reinterpret_cast<const uint4*>(p);
    d[0] = b2f_bits((u16)(w.x & 0xffff)); d[1] = b2f_bits((u16)(w.x >> 16));
    d[2] = b2f_bits((u16)(w.y & 0xffff)); d[3] = b2f_bits((u16)(w.y >> 16));
    d[4] = b2f_bits((u16)(w.z & 0xffff)); d[5] = b2f_bits((u16)(w.z >> 16));
    d[6] = b2f_bits((u16)(w.w & 0xffff)); d[7] = b2f_bits((u16)(w.w >> 16));
}
// async global->LDS, 16B per lane (lds dest must be wave-uniform base + lane*16)
__device__ __forceinline__ void gload16(const void* g, void* l) {
    __builtin_amdgcn_global_load_lds(
        (const __attribute__((address_space(1))) void*)g,
        (__attribute__((address_space(3))) void*)l, 16, 0, 0);
}

// ---------------- Weight transpose+convert: W[k][n] f32 -> WT[n][k] bf16 ----
// q-columns (n < DIM) of Wqkv are pre-scaled by QSCALE (f32, before bf16
// rounding) so attention computes p = 2^s with no per-score multiply.
__global__ __launch_bounds__(256) void convert_kernel(
        const float* __restrict__ Wqkv, const float* __restrict__ Wproj,
        bf16* __restrict__ WTq, bf16* __restrict__ WTp) {
    const int n = blockIdx.x;
    const int k = threadIdx.x;
    if (n < QKVN) {
        float v = Wqkv[(size_t)k * QKVN + n];
        if (n < DIM) v *= QSCALE;
        WTq[(size_t)n * DIM + k] = __float2bfloat16(v);
    } else {
        const int n2 = n - QKVN;
        WTp[(size_t)n2 * DIM + k] = __float2bfloat16(Wproj[(size_t)k * DIM + n2]);
    }
}

// ---------------- LayerNorm: one WAVE per row, float4 per lane -------------
// 64 lanes x float4 = 256 elems = one row. No LDS, no barriers: 6-step
// __shfl_xor reductions. Grid-stride over rows (16 rows/wave at 2048 blocks)
// so loads from successive rows overlap (MLP), gamma/beta hoisted to regs.
__global__ __launch_bounds__(256) void ln_kernel(
        const float* __restrict__ x, const float* __restrict__ gamma,
        const float* __restrict__ beta, bf16* __restrict__ xn,
        size_t x_off, int nrows) {
    const int t = threadIdx.x;
    const int wv = t >> 6, lane = t & 63;
    const int nwaves = gridDim.x << 2;
    const int wid = (blockIdx.x << 2) + wv;

    const float4 g4 = *reinterpret_cast<const float4*>(gamma + lane * 4);
    const float4 b4 = *reinterpret_cast<const float4*>(beta + lane * 4);

    for (int row = wid; row < nrows; row += nwaves) {
        const float4 v = *reinterpret_cast<const float4*>(
            x + x_off + (size_t)row * DIM + lane * 4);

        float s = v.x + v.y + v.z + v.w;
        #pragma unroll
        for (int off = 32; off > 0; off >>= 1) s += __shfl_xor(s, off, 64);
        const float mean = s * (1.0f / DIM);

        const float dx = v.x - mean, dy = v.y - mean;
        const float dz = v.z - mean, dw = v.w - mean;
        float s2 = dx * dx + dy * dy + dz * dz + dw * dw;
        #pragma unroll
        for (int off = 32; off > 0; off >>= 1) s2 += __shfl_xor(s2, off, 64);
        const float rstd = rsqrtf(s2 * (1.0f / DIM) + 1e-5f);

        uint2 o;
        o.x = pack2(dx * rstd * g4.x + b4.x, dy * rstd * g4.y + b4.y);
        o.y = pack2(dz * rstd * g4.z + b4.z, dw * rstd * g4.w + b4.w);
        *reinterpret_cast<uint2*>(xn + (size_t)row * DIM + lane * 4) = o;
    }
}

// ---------------- MFMA GEMM: C[M,N] = A[M,256] @ WT^T + bias (+resid) ------
// A: bf16 row-major [M][256]. WT: bf16 [N][256] (i.e. W transposed).
// 128x128 tile, BK=32, 4 waves in 2x2, each wave 4x4 mfma_f32_16x16x32_bf16.
// OUT_F32: f32 store + resid (final proj), direct stores (64B segments, fine).
// OUT_F32==0 (qkv): SWAPPED mfma operands -> lane owns 4 consecutive N-cols
// of one M-row; stage per-wave 64x64 bf16 tile in LDS (XOR-swizzled cols),
// read back 16B/lane -> 128B-contiguous global stores (fixes 2x write ampl).
// qkv path also scales bias cols < DIM by QSCALE (matches scaled Wq).
// Both paths: XCD-chunked block swizzle so blocks sharing an A-panel land on
// the same XCD L2 (fixes A re-fetch amplification).
template<int OUT_F32>
__global__ __launch_bounds__(256) void gemm_mfma(
        const bf16* __restrict__ A, const bf16* __restrict__ WT,
        const float* __restrict__ bias, const float* __restrict__ resid,
        void* __restrict__ Cout, int N) {
    __shared__ __align__(16) bf16 As[128][32];   // 8 KiB
    __shared__ __align__(16) bf16 Bs[128][32];   // 8 KiB

    const int tid = threadIdx.x;
    const int lane = tid & 63, wave = tid >> 6;
    const int wm = (wave >> 1) * 64, wn = (wave & 1) * 64;
    const int m = lane & 15, quad = lane >> 4;

    // XCD-chunked swizzle (nwg % 8 == 0 for both grids used)
    const int nwg = gridDim.x * gridDim.y;
    const int L = blockIdx.y * gridDim.x + blockIdx.x;
    const int tile = (L & 7) * (nwg >> 3) + (L >> 3);
    const int bx = tile % gridDim.x, by = tile / gridDim.x;
    const int row0 = by * 128, col0 = bx * 128;

    floatx4 acc[4][4] = {};

    // staging chunk ids: c covers 16B = 8 elems; row = c>>2, koff = (c&3)*8
    const int c0 = tid, c1 = tid + 256;
    const int r0_ = c0 >> 2, o0 = (c0 & 3) * 8;
    const int r1_ = c1 >> 2, o1 = (c1 & 3) * 8;

    for (int k0 = 0; k0 < DIM; k0 += 32) {
        __syncthreads();
        gload16(A  + (size_t)(row0 + r0_) * DIM + k0 + o0, (bf16*)As + c0 * 8);
        gload16(A  + (size_t)(row0 + r1_) * DIM + k0 + o1, (bf16*)As + c1 * 8);
        gload16(WT + (size_t)(col0 + r0_) * DIM + k0 + o0, (bf16*)Bs + c0 * 8);
        gload16(WT + (size_t)(col0 + r1_) * DIM + k0 + o1, (bf16*)Bs + c1 * 8);
        __syncthreads();

        short8 af[4], bfr[4];
        #pragma unroll
        for (int i = 0; i < 4; i++)
            af[i] = *reinterpret_cast<const short8*>(&As[wm + i * 16 + m][quad * 8]);
        #pragma unroll
        for (int j = 0; j < 4; j++)
            bfr[j] = *reinterpret_cast<const short8*>(&Bs[wn + j * 16 + m][quad * 8]);
        #pragma unroll
        for (int i = 0; i < 4; i++) {
            #pragma unroll
            for (int j = 0; j < 4; j++) {
                if constexpr (OUT_F32) {
                    acc[i][j] = __builtin_amdgcn_mfma_f32_16x16x32_bf16(
                        af[i], bfr[j], acc[i][j], 0, 0, 0);
                } else {
                    // swapped: D^T -> col(lane&15)=M-row, row(quad*4+r)=N-col
                    acc[i][j] = __builtin_amdgcn_mfma_f32_16x16x32_bf16(
                        bfr[j], af[i], acc[i][j], 0, 0, 0);
                }
            }
        }
    }

    if constexpr (OUT_F32) {
        // C/D layout col = lane&15 (N), row = quad*4 + reg (M) (m89-verified)
        #pragma unroll
        for (int j = 0; j < 4; j++) {
            const int col = col0 + wn + j * 16 + m;
            const float bj = bias[col];
            #pragma unroll
            for (int i = 0; i < 4; i++) {
                #pragma unroll
                for (int r = 0; r < 4; r++) {
                    const int row = row0 + wm + i * 16 + quad * 4 + r;
                    ((float*)Cout)[(size_t)row * N + col] =
                        acc[i][j][r] + bj + resid[(size_t)row * N + col];
                }
            }
        }
    } else {
        // swapped layout: lane holds M-row (i*16+m), N-cols j*16+quad*4..+3
        __shared__ __align__(16) u16 Cs[4][64][64];   // 32 KiB, per-wave tile
        #pragma unroll
        for (int i = 0; i < 4; i++) {
            const int rr = i * 16 + m;
            const int sx = (m & 7) << 3;    // XOR swizzle (bits 3-5 of col)
            #pragma unroll
            for (int j = 0; j < 4; j++) {
                const int cc = j * 16 + quad * 4;
                const int ccol = col0 + wn + cc;
                float4 bj = *reinterpret_cast<const float4*>(&bias[ccol]);
                if (ccol < DIM) {   // q-columns: bias scaled like Wq
                    bj.x *= QSCALE; bj.y *= QSCALE;
                    bj.z *= QSCALE; bj.w *= QSCALE;
                }
                u32* p = reinterpret_cast<u32*>(&Cs[wave][rr][cc ^ sx]);
                p[0] = pack2(acc[i][j][0] + bj.x, acc[i][j][1] + bj.y);
                p[1] = pack2(acc[i][j][2] + bj.z, acc[i][j][3] + bj.w);
            }
        }
        // per-wave region, same-wave RAW -> no barrier needed
        #pragma unroll
        for (int p = 0; p < 8; p++) {
            const int rr = p * 8 + (lane >> 3);
            const int cc = (lane & 7) * 8;
            const uint4 v = *reinterpret_cast<const uint4*>(
                &Cs[wave][rr][cc ^ ((rr & 7) << 3)]);
            *reinterpret_cast<uint4*>(
                &((bf16*)Cout)[(size_t)(row0 + wm + rr) * N + col0 + wn + cc]) = v;
        }
    }
}

// ---------------- Stripe attention, MFMA version ----------------
// grid = dim3(512, nb): x = dir(2) x stripe(64) x head(4); y = batch image.
// Block: 256 thr = 4 waves; wave w owns query rows [w*64, w*64+64).
// Round-7 structure (lockstep barriers, key-permuted packed P-store) with
// two arithmetic substitutions (r7 post-mortem: VALU +40% from libm exp2f;
// cvt chain ~2500 cyc/wave was the largest VALU term):
//  (a) p = 2^s via raw v_exp_f32 (q pre-scaled by QSCALE in qkv GEMM).
//  (b) P pack via v_cvt_pk_bf16_f32 (1 op/pair, HW RNE).
__global__ __launch_bounds__(256) void attn_kernel(
        const bf16* __restrict__ qkv, bf16* __restrict__ h) {
    __shared__ __align__(16) u16 Ks[SEQ][HD];       // 16 KiB, linear (gload16)
    __shared__ __align__(16) u16 Vt[HD][264];       // 16.5 KiB, transposed+padded
    __shared__ __align__(16) u16 Ps[4][64][40];     // 20 KiB, per-wave P chunk

    const int bid = blockIdx.x;
    const int head = bid & 3;
    const int s = (bid >> 2) & 63;
    const int dir = bid >> 8;
    const int b = blockIdx.y;

    const int t = threadIdx.x;
    const int w = t >> 6, lane = t & 63;
    const int m = lane & 15, quad = lane >> 4;
    const int qoff = dir * 128 + head * HD;

    // spatial row of stripe-local index idx (0..255)
    auto row_of = [&](int idx) -> size_t {
        const int al = idx >> 7, l = idx & 127;
        int hp, wp;
        if (dir == 0) { hp = 2 * s + al; wp = l; }
        else          { wp = 2 * s + al; hp = l; }
        return ((size_t)(b * 128 + hp)) * 128 + wp;
    };

    // --- stage K linearly into LDS: 4 x 16B per thread (per-lane global src) ---
    #pragma unroll
    for (int j = 0; j < 4; j++) {
        const int e = t * 8 + j * 2048;      // flat element offset into Ks
        const int key = e >> 5;
        const int ko = e & 31;
        gload16(qkv + row_of(key) * QKVN + 256 + qoff + ko, (u16*)Ks + e);
    }

    // --- stage V transposed + key-permuted: thread t (key t) scatters to
    //     column vcol = c*32 + ((kk&15)<<1 | kk>>4), matching P's slot order.
    {
        const int vcol = (t & 0xE0) | (((t & 15) << 1) | ((t >> 4) & 1));
        const bf16* vp = qkv + row_of(t) * QKVN + 512 + qoff;
        const uint4 v0 = *reinterpret_cast<const uint4*>(vp);
        const uint4 v1 = *reinterpret_cast<const uint4*>(vp + 8);
        const uint4 v2 = *reinterpret_cast<const uint4*>(vp + 16);
        const uint4 v3 = *reinterpret_cast<const uint4*>(vp + 24);
        const u32 ww[16] = { v0.x, v0.y, v0.z, v0.w, v1.x, v1.y, v1.z, v1.w,
                             v2.x, v2.y, v2.z, v2.w, v3.x, v3.y, v3.z, v3.w };
        #pragma unroll
        for (int d = 0; d < 16; d++) {
            Vt[2 * d][vcol]     = (u16)(ww[d] & 0xffff);
            Vt[2 * d + 1][vcol] = (u16)(ww[d] >> 16);
        }
    }

    // --- Q fragments in registers: rows w*64 + i*16 + m, k = quad*8 ---
    // (q is pre-scaled by QSCALE from the qkv GEMM)
    short8 qf[4];
    #pragma unroll
    for (int i = 0; i < 4; i++)
        qf[i] = *reinterpret_cast<const short8*>(
            qkv + row_of(w * 64 + i * 16 + m) * QKVN + qoff + quad * 8);

    __syncthreads();   // staging visible (also drains gload16 vmcnt)

    floatx4 acc[4][2] = {};
    floatx4 rs[4] = {};

    for (int c = 0; c < 8; c++) {
        // K fragments for this 32-key chunk (B-frag rows = key index)
        const short8 kf0 = *reinterpret_cast<const short8*>(&Ks[c * 32 + m][quad * 8]);
        const short8 kf1 = *reinterpret_cast<const short8*>(&Ks[c * 32 + 16 + m][quad * 8]);

        #pragma unroll
        for (int i = 0; i < 4; i++) {
            const floatx4 z = {};
            floatx4 s0 = __builtin_amdgcn_mfma_f32_16x16x32_bf16(qf[i], kf0, z, 0, 0, 0);
            floatx4 s1 = __builtin_amdgcn_mfma_f32_16x16x32_bf16(qf[i], kf1, z, 0, 0, 0);
            #pragma unroll
            for (int r = 0; r < 4; r++) {
                const float p0 = fexp2(s0[r]);     // pre-scaled q: 1 op/score
                const float p1 = fexp2(s1[r]);
                rs[i][r] += p0 + p1;
                // C-layout row = i*16 + quad*4 + r; keys m & 16+m -> slots
                // 2m, 2m+1 (permuted): one cvt_pk + one u32 store.
                *reinterpret_cast<u32*>(
                    &Ps[w][i * 16 + quad * 4 + r][2 * m]) = cvtpk(p0, p1);
            }
        }
        __syncthreads();   // lockstep phases (measured faster than free-run)

        // V fragments: B[n=hd][slot] = Vt[hd][slot], slots match P's order
        const short8 vf0 = *reinterpret_cast<const short8*>(&Vt[m][c * 32 + quad * 8]);
        const short8 vf1 = *reinterpret_cast<const short8*>(&Vt[16 + m][c * 32 + quad * 8]);

        #pragma unroll
        for (int i = 0; i < 4; i++) {
            const short8 pf = *reinterpret_cast<const short8*>(&Ps[w][i * 16 + m][quad * 8]);
            acc[i][0] = __builtin_amdgcn_mfma_f32_16x16x32_bf16(pf, vf0, acc[i][0], 0, 0, 0);
            acc[i][1] = __builtin_amdgcn_mfma_f32_16x16x32_bf16(pf, vf1, acc[i][1], 0, 0, 0);
        }
        __syncthreads();   // Ps reads done before next chunk's writes (WAR)
    }

    // --- row-sum reduce across the 16 lanes of each quad (xor 1,2,4,8) ---
    #pragma unroll
    for (int i = 0; i < 4; i++) {
        #pragma unroll
        for (int r = 0; r < 4; r++) {
            float v = rs[i][r];
            v += __shfl_xor(v, 1);
            v += __shfl_xor(v, 2);
            v += __shfl_xor(v, 4);
            v += __shfl_xor(v, 8);
            rs[i][r] = v;
        }
    }

    // --- epilogue: out[q][hd] = acc / lsum; col = h*16+m, row = quad*4+r ---
    #pragma unroll
    for (int i = 0; i < 4; i++) {
        #pragma unroll
        for (int r = 0; r < 4; r++) {
            const float inv = 1.0f / rs[i][r];
            bf16* op = h + row_of(w * 64 + i * 16 + quad * 4 + r) * DIM + qoff;
            op[m]      = __float2bfloat16(acc[i][0][r] * inv);
            op[16 + m] = __float2bfloat16(acc[i][1][r] * inv);
        }
    }
}

extern "C" void kernel_launch(void* const* d_in, const int* in_sizes, int n_in,
                              void* d_out, int out_size, void* d_ws, size_t ws_size,
                              hipStream_t stream) {
    const float* x     = (const float*)d_in[0];
    const float* Wqkv  = (const float*)d_in[1];
    const float* bqkv  = (const float*)d_in[2];
    const float* Wproj = (const float*)d_in[3];
    const float* bproj = (const float*)d_in[4];
    const float* gamma = (const float*)d_in[5];
    const float* beta  = (const float*)d_in[6];
    char* ws = (char*)d_ws;

    const size_t MB256 = (size_t)268435456;
    if (ws_size >= MB256 + 524288) {
        // [0,64M): xn, later h   [64M,256M): qkv   [256M,+512K): WTq|WTp
        bf16* xn_h = (bf16*)ws;
        bf16* qkv  = (bf16*)(ws + (size_t)NROWS * DIM * 2);
        bf16* WTq  = (bf16*)(ws + MB256);
        bf16* WTp  = WTq + (size_t)QKVN * DIM;

        convert_kernel<<<QKVN + DIM, 256, 0, stream>>>(Wqkv, Wproj, WTq, WTp);
        ln_kernel<<<2048, 256, 0, stream>>>(x, gamma, beta, xn_h, 0, NROWS);
        gemm_mfma<0><<<dim3(QKVN / 128, NROWS / 128), 256, 0, stream>>>(
            xn_h, WTq, bqkv, nullptr, qkv, QKVN);
        attn_kernel<<<dim3(512, 8), 256, 0, stream>>>(qkv, xn_h);
        gemm_mfma<1><<<dim3(DIM / 128, NROWS / 128), 256, 0, stream>>>(
            xn_h, WTp, bproj, x, d_out, DIM);
    } else {
        // Per-image path: WT @0 (512K), xn_b @1M (8M), qkv_b @9M (24M), h_b @33M (8M)
        const int MB = NROWS / 8;   // 16384 rows per image
        bf16* WTq   = (bf16*)ws;
        bf16* WTp   = WTq + (size_t)QKVN * DIM;
        bf16* xn_b  = (bf16*)(ws + (size_t)1048576);
        bf16* qkv_b = (bf16*)(ws + (size_t)9 * 1048576);
        bf16* h_b   = (bf16*)(ws + (size_t)33 * 1048576);

        convert_kernel<<<QKVN + DIM, 256, 0, stream>>>(Wqkv, Wproj, WTq, WTp);
        for (int b = 0; b < 8; b++) {
            const size_t ro = (size_t)b * MB * DIM;
            ln_kernel<<<2048, 256, 0, stream>>>(x, gamma, beta, xn_b, ro, MB);
            gemm_mfma<0><<<dim3(QKVN / 128, MB / 128), 256, 0, stream>>>(
                xn_b, WTq, bqkv, nullptr, qkv_b, QKVN);
            attn_kernel<<<dim3(512, 1), 256, 0, stream>>>(qkv_b, h_b);
            gemm_mfma<1><<<dim3(DIM / 128, MB / 128), 256, 0, stream>>>(
                h_b, WTp, bproj, x + ro, (float*)d_out + ro, DIM);
        }
    }
}

// Round 9
// 489.078 us; speedup vs baseline: 1.1105x; 1.0043x over previous
//
#include <hip/hip_runtime.h>
#include <hip/hip_bf16.h>

typedef __hip_bfloat16 bf16;
typedef unsigned short u16;
typedef unsigned int u32;
typedef __attribute__((ext_vector_type(8))) short short8;   // 8 x bf16 (4 VGPRs)
typedef __attribute__((ext_vector_type(4))) float floatx4;  // 4 x f32 acc

#define NROWS (8*128*128)   // 131072 spatial positions
#define DIM 256
#define QKVN 768
#define HD 32
#define SEQ 256             // stripe sequence length = sw(2) * 128
#define QSCALE 0.25503494f  // (1/sqrt(32)) * log2(e), folded into Wq/bq

__device__ __forceinline__ float b2f_bits(u16 u) {
    union { float f; u32 i; } x; x.i = ((u32)u) << 16; return x.f;
}
__device__ __forceinline__ u16 f2b_bits(float f) {
    bf16 h = __float2bfloat16(f);
    return *reinterpret_cast<u16*>(&h);
}
__device__ __forceinline__ u32 pack2(float a, float b) {
    return ((u32)f2b_bits(b) << 16) | (u32)f2b_bits(a);
}
// native transcendental: D = 2^x (1 VALU op; exp2f libm path measured +40% VALU, r7)
__device__ __forceinline__ float fexp2(float x) {
    float r;
    asm("v_exp_f32 %0, %1" : "=v"(r) : "v"(x));
    return r;
}
// HW packed bf16 convert (RNE): lo16 = bf16(a), hi16 = bf16(b) (T12 primitive)
__device__ __forceinline__ u32 cvtpk(float a, float b) {
    u32 r;
    asm("v_cvt_pk_bf16_f32 %0, %1, %2" : "=v"(r) : "v"(a), "v"(b));
    return r;
}
// load 8 consecutive bf16 (16B) -> 8 floats
__device__ __forceinline__ void load8f(const bf16* p, float* d) {
    uint4 w = *reinterpret_cast<const uint4*>(p);
    d[0] = b2f_bits((u16)(w.x & 0xffff)); d[1] = b2f_bits((u16)(w.x >> 16));
    d[2] = b2f_bits((u16)(w.y & 0xffff)); d[3] = b2f_bits((u16)(w.y >> 16));
    d[4] = b2f_bits((u16)(w.z & 0xffff)); d[5] = b2f_bits((u16)(w.z >> 16));
    d[6] = b2f_bits((u16)(w.w & 0xffff)); d[7] = b2f_bits((u16)(w.w >> 16));
}
// async global->LDS, 16B per lane (lds dest must be wave-uniform base + lane*16)
__device__ __forceinline__ void gload16(const void* g, void* l) {
    __builtin_amdgcn_global_load_lds(
        (const __attribute__((address_space(1))) void*)g,
        (__attribute__((address_space(3))) void*)l, 16, 0, 0);
}

// ---------------- Weight transpose+convert: W[k][n] f32 -> WT[n][k] bf16 ----
// q-columns (n < DIM) of Wqkv are pre-scaled by QSCALE (f32, before bf16
// rounding) so attention computes p = 2^s with no per-score multiply.
__global__ __launch_bounds__(256) void convert_kernel(
        const float* __restrict__ Wqkv, const float* __restrict__ Wproj,
        bf16* __restrict__ WTq, bf16* __restrict__ WTp) {
    const int n = blockIdx.x;
    const int k = threadIdx.x;
    if (n < QKVN) {
        float v = Wqkv[(size_t)k * QKVN + n];
        if (n < DIM) v *= QSCALE;
        WTq[(size_t)n * DIM + k] = __float2bfloat16(v);
    } else {
        const int n2 = n - QKVN;
        WTp[(size_t)n2 * DIM + k] = __float2bfloat16(Wproj[(size_t)k * DIM + n2]);
    }
}

// ---------------- LayerNorm: one WAVE per row, float4 per lane -------------
// 64 lanes x float4 = 256 elems = one row. No LDS, no barriers: 6-step
// __shfl_xor reductions. Grid-stride over rows (16 rows/wave at 2048 blocks)
// so loads from successive rows overlap (MLP), gamma/beta hoisted to regs.
__global__ __launch_bounds__(256) void ln_kernel(
        const float* __restrict__ x, const float* __restrict__ gamma,
        const float* __restrict__ beta, bf16* __restrict__ xn,
        size_t x_off, int nrows) {
    const int t = threadIdx.x;
    const int wv = t >> 6, lane = t & 63;
    const int nwaves = gridDim.x << 2;
    const int wid = (blockIdx.x << 2) + wv;

    const float4 g4 = *reinterpret_cast<const float4*>(gamma + lane * 4);
    const float4 b4 = *reinterpret_cast<const float4*>(beta + lane * 4);

    for (int row = wid; row < nrows; row += nwaves) {
        const float4 v = *reinterpret_cast<const float4*>(
            x + x_off + (size_t)row * DIM + lane * 4);

        float s = v.x + v.y + v.z + v.w;
        #pragma unroll
        for (int off = 32; off > 0; off >>= 1) s += __shfl_xor(s, off, 64);
        const float mean = s * (1.0f / DIM);

        const float dx = v.x - mean, dy = v.y - mean;
        const float dz = v.z - mean, dw = v.w - mean;
        float s2 = dx * dx + dy * dy + dz * dz + dw * dw;
        #pragma unroll
        for (int off = 32; off > 0; off >>= 1) s2 += __shfl_xor(s2, off, 64);
        const float rstd = rsqrtf(s2 * (1.0f / DIM) + 1e-5f);

        uint2 o;
        o.x = pack2(dx * rstd * g4.x + b4.x, dy * rstd * g4.y + b4.y);
        o.y = pack2(dz * rstd * g4.z + b4.z, dw * rstd * g4.w + b4.w);
        *reinterpret_cast<uint2*>(xn + (size_t)row * DIM + lane * 4) = o;
    }
}

// ---------------- MFMA GEMM: C[M,N] = A[M,256] @ WT^T + bias (+resid) ------
// A: bf16 row-major [M][256]. WT: bf16 [N][256] (i.e. W transposed).
// 128x128 tile, BK=32, 4 waves in 2x2, each wave 4x4 mfma_f32_16x16x32_bf16.
// OUT_F32: f32 store + resid (final proj), direct stores (64B segments, fine).
// OUT_F32==0 (qkv): SWAPPED mfma operands -> lane owns 4 consecutive N-cols
// of one M-row. Epilogue stages bf16 through LDS that ALIASES As/Bs (r8:
// the 32K separate Cs buffer capped occupancy at 3 blocks/CU, 27% measured;
// 16K total -> ~7 blocks/CU, VGPR-limited). Each wave's 64x64 tile goes in
// two 64x32 passes through its 4K share; one barrier after the k-loop (all
// waves done reading As/Bs), epilogue DS ops are same-wave in-order.
// Byte-XOR (row&3)<<4 on write AND read (involution, bijective in 64B row).
// qkv path also scales bias cols < DIM by QSCALE (matches scaled Wq).
// Both paths: XCD-chunked block swizzle so blocks sharing an A-panel land on
// the same XCD L2 (fixes A re-fetch amplification).
template<int OUT_F32>
__global__ __launch_bounds__(256) void gemm_mfma(
        const bf16* __restrict__ A, const bf16* __restrict__ WT,
        const float* __restrict__ bias, const float* __restrict__ resid,
        void* __restrict__ Cout, int N) {
    __shared__ __align__(16) bf16 SMEM[2][128][32];   // 16 KiB: As | Bs
    bf16 (&As)[128][32] = SMEM[0];
    bf16 (&Bs)[128][32] = SMEM[1];

    const int tid = threadIdx.x;
    const int lane = tid & 63, wave = tid >> 6;
    const int wm = (wave >> 1) * 64, wn = (wave & 1) * 64;
    const int m = lane & 15, quad = lane >> 4;

    // XCD-chunked swizzle (nwg % 8 == 0 for both grids used)
    const int nwg = gridDim.x * gridDim.y;
    const int L = blockIdx.y * gridDim.x + blockIdx.x;
    const int tile = (L & 7) * (nwg >> 3) + (L >> 3);
    const int bx = tile % gridDim.x, by = tile / gridDim.x;
    const int row0 = by * 128, col0 = bx * 128;

    floatx4 acc[4][4] = {};

    // staging chunk ids: c covers 16B = 8 elems; row = c>>2, koff = (c&3)*8
    const int c0 = tid, c1 = tid + 256;
    const int r0_ = c0 >> 2, o0 = (c0 & 3) * 8;
    const int r1_ = c1 >> 2, o1 = (c1 & 3) * 8;

    for (int k0 = 0; k0 < DIM; k0 += 32) {
        __syncthreads();
        gload16(A  + (size_t)(row0 + r0_) * DIM + k0 + o0, (bf16*)As + c0 * 8);
        gload16(A  + (size_t)(row0 + r1_) * DIM + k0 + o1, (bf16*)As + c1 * 8);
        gload16(WT + (size_t)(col0 + r0_) * DIM + k0 + o0, (bf16*)Bs + c0 * 8);
        gload16(WT + (size_t)(col0 + r1_) * DIM + k0 + o1, (bf16*)Bs + c1 * 8);
        __syncthreads();

        short8 af[4], bfr[4];
        #pragma unroll
        for (int i = 0; i < 4; i++)
            af[i] = *reinterpret_cast<const short8*>(&As[wm + i * 16 + m][quad * 8]);
        #pragma unroll
        for (int j = 0; j < 4; j++)
            bfr[j] = *reinterpret_cast<const short8*>(&Bs[wn + j * 16 + m][quad * 8]);
        #pragma unroll
        for (int i = 0; i < 4; i++) {
            #pragma unroll
            for (int j = 0; j < 4; j++) {
                if constexpr (OUT_F32) {
                    acc[i][j] = __builtin_amdgcn_mfma_f32_16x16x32_bf16(
                        af[i], bfr[j], acc[i][j], 0, 0, 0);
                } else {
                    // swapped: D^T -> col(lane&15)=M-row, row(quad*4+r)=N-col
                    acc[i][j] = __builtin_amdgcn_mfma_f32_16x16x32_bf16(
                        bfr[j], af[i], acc[i][j], 0, 0, 0);
                }
            }
        }
    }

    if constexpr (OUT_F32) {
        // C/D layout col = lane&15 (N), row = quad*4 + reg (M) (m89-verified)
        #pragma unroll
        for (int j = 0; j < 4; j++) {
            const int col = col0 + wn + j * 16 + m;
            const float bj = bias[col];
            #pragma unroll
            for (int i = 0; i < 4; i++) {
                #pragma unroll
                for (int r = 0; r < 4; r++) {
                    const int row = row0 + wm + i * 16 + quad * 4 + r;
                    ((float*)Cout)[(size_t)row * N + col] =
                        acc[i][j][r] + bj + resid[(size_t)row * N + col];
                }
            }
        }
    } else {
        // swapped layout: lane holds M-row (i*16+m), N-cols j*16+quad*4..+3.
        // Stage through per-wave 4K LDS region aliasing As/Bs, two 64x32
        // column-half passes; 64B-contiguous sector-aligned global stores.
        __syncthreads();   // all waves done with k-loop LDS reads
        char* Cw = (char*)SMEM + wave * 4096;   // 64 rows x 64 B
        #pragma unroll
        for (int jh = 0; jh < 2; jh++) {
            #pragma unroll
            for (int i = 0; i < 4; i++) {
                const int rr = i * 16 + m;
                const int swz = (m & 3) << 4;
                #pragma unroll
                for (int jj = 0; jj < 2; jj++) {
                    const int j = jh * 2 + jj;
                    const int ccol = col0 + wn + j * 16 + quad * 4;
                    float4 bj = *reinterpret_cast<const float4*>(&bias[ccol]);
                    if (ccol < DIM) {   // q-columns: bias scaled like Wq
                        bj.x *= QSCALE; bj.y *= QSCALE;
                        bj.z *= QSCALE; bj.w *= QSCALE;
                    }
                    u32* p = reinterpret_cast<u32*>(
                        Cw + rr * 64 + ((jj * 32 + quad * 8) ^ swz));
                    p[0] = pack2(acc[i][j][0] + bj.x, acc[i][j][1] + bj.y);
                    p[1] = pack2(acc[i][j][2] + bj.z, acc[i][j][3] + bj.w);
                }
            }
            // read back (same wave, in-order DS): 16B/lane, 4 x 16 rows
            #pragma unroll
            for (int p = 0; p < 4; p++) {
                const int rr = p * 16 + (lane >> 2);
                const int ch = lane & 3;
                const uint4 v = *reinterpret_cast<const uint4*>(
                    Cw + rr * 64 + ((ch * 16) ^ ((rr & 3) << 4)));
                *reinterpret_cast<uint4*>(
                    &((bf16*)Cout)[(size_t)(row0 + wm + rr) * N +
                                   col0 + wn + jh * 32 + ch * 8]) = v;
            }
        }
    }
}

// ---------------- Stripe attention, MFMA version ----------------
// grid = dim3(512, nb): x = dir(2) x stripe(64) x head(4); y = batch image.
// Block: 256 thr = 4 waves; wave w owns query rows [w*64, w*64+64).
// Lockstep barriers, key-permuted packed P-store, raw v_exp_f32 +
// v_cvt_pk_bf16_f32 (r8: VALU 81 -> dropped attn off top-5).
__global__ __launch_bounds__(256) void attn_kernel(
        const bf16* __restrict__ qkv, bf16* __restrict__ h) {
    __shared__ __align__(16) u16 Ks[SEQ][HD];       // 16 KiB, linear (gload16)
    __shared__ __align__(16) u16 Vt[HD][264];       // 16.5 KiB, transposed+padded
    __shared__ __align__(16) u16 Ps[4][64][40];     // 20 KiB, per-wave P chunk

    const int bid = blockIdx.x;
    const int head = bid & 3;
    const int s = (bid >> 2) & 63;
    const int dir = bid >> 8;
    const int b = blockIdx.y;

    const int t = threadIdx.x;
    const int w = t >> 6, lane = t & 63;
    const int m = lane & 15, quad = lane >> 4;
    const int qoff = dir * 128 + head * HD;

    // spatial row of stripe-local index idx (0..255)
    auto row_of = [&](int idx) -> size_t {
        const int al = idx >> 7, l = idx & 127;
        int hp, wp;
        if (dir == 0) { hp = 2 * s + al; wp = l; }
        else          { wp = 2 * s + al; hp = l; }
        return ((size_t)(b * 128 + hp)) * 128 + wp;
    };

    // --- stage K linearly into LDS: 4 x 16B per thread (per-lane global src) ---
    #pragma unroll
    for (int j = 0; j < 4; j++) {
        const int e = t * 8 + j * 2048;      // flat element offset into Ks
        const int key = e >> 5;
        const int ko = e & 31;
        gload16(qkv + row_of(key) * QKVN + 256 + qoff + ko, (u16*)Ks + e);
    }

    // --- stage V transposed + key-permuted: thread t (key t) scatters to
    //     column vcol = c*32 + ((kk&15)<<1 | kk>>4), matching P's slot order.
    {
        const int vcol = (t & 0xE0) | (((t & 15) << 1) | ((t >> 4) & 1));
        const bf16* vp = qkv + row_of(t) * QKVN + 512 + qoff;
        const uint4 v0 = *reinterpret_cast<const uint4*>(vp);
        const uint4 v1 = *reinterpret_cast<const uint4*>(vp + 8);
        const uint4 v2 = *reinterpret_cast<const uint4*>(vp + 16);
        const uint4 v3 = *reinterpret_cast<const uint4*>(vp + 24);
        const u32 ww[16] = { v0.x, v0.y, v0.z, v0.w, v1.x, v1.y, v1.z, v1.w,
                             v2.x, v2.y, v2.z, v2.w, v3.x, v3.y, v3.z, v3.w };
        #pragma unroll
        for (int d = 0; d < 16; d++) {
            Vt[2 * d][vcol]     = (u16)(ww[d] & 0xffff);
            Vt[2 * d + 1][vcol] = (u16)(ww[d] >> 16);
        }
    }

    // --- Q fragments in registers: rows w*64 + i*16 + m, k = quad*8 ---
    // (q is pre-scaled by QSCALE from the qkv GEMM)
    short8 qf[4];
    #pragma unroll
    for (int i = 0; i < 4; i++)
        qf[i] = *reinterpret_cast<const short8*>(
            qkv + row_of(w * 64 + i * 16 + m) * QKVN + qoff + quad * 8);

    __syncthreads();   // staging visible (also drains gload16 vmcnt)

    floatx4 acc[4][2] = {};
    floatx4 rs[4] = {};

    for (int c = 0; c < 8; c++) {
        // K fragments for this 32-key chunk (B-frag rows = key index)
        const short8 kf0 = *reinterpret_cast<const short8*>(&Ks[c * 32 + m][quad * 8]);
        const short8 kf1 = *reinterpret_cast<const short8*>(&Ks[c * 32 + 16 + m][quad * 8]);

        #pragma unroll
        for (int i = 0; i < 4; i++) {
            const floatx4 z = {};
            floatx4 s0 = __builtin_amdgcn_mfma_f32_16x16x32_bf16(qf[i], kf0, z, 0, 0, 0);
            floatx4 s1 = __builtin_amdgcn_mfma_f32_16x16x32_bf16(qf[i], kf1, z, 0, 0, 0);
            #pragma unroll
            for (int r = 0; r < 4; r++) {
                const float p0 = fexp2(s0[r]);     // pre-scaled q: 1 op/score
                const float p1 = fexp2(s1[r]);
                rs[i][r] += p0 + p1;
                // C-layout row = i*16 + quad*4 + r; keys m & 16+m -> slots
                // 2m, 2m+1 (permuted): one cvt_pk + one u32 store.
                *reinterpret_cast<u32*>(
                    &Ps[w][i * 16 + quad * 4 + r][2 * m]) = cvtpk(p0, p1);
            }
        }
        __syncthreads();   // lockstep phases (measured faster than free-run)

        // V fragments: B[n=hd][slot] = Vt[hd][slot], slots match P's order
        const short8 vf0 = *reinterpret_cast<const short8*>(&Vt[m][c * 32 + quad * 8]);
        const short8 vf1 = *reinterpret_cast<const short8*>(&Vt[16 + m][c * 32 + quad * 8]);

        #pragma unroll
        for (int i = 0; i < 4; i++) {
            const short8 pf = *reinterpret_cast<const short8*>(&Ps[w][i * 16 + m][quad * 8]);
            acc[i][0] = __builtin_amdgcn_mfma_f32_16x16x32_bf16(pf, vf0, acc[i][0], 0, 0, 0);
            acc[i][1] = __builtin_amdgcn_mfma_f32_16x16x32_bf16(pf, vf1, acc[i][1], 0, 0, 0);
        }
        __syncthreads();   // Ps reads done before next chunk's writes (WAR)
    }

    // --- row-sum reduce across the 16 lanes of each quad (xor 1,2,4,8) ---
    #pragma unroll
    for (int i = 0; i < 4; i++) {
        #pragma unroll
        for (int r = 0; r < 4; r++) {
            float v = rs[i][r];
            v += __shfl_xor(v, 1);
            v += __shfl_xor(v, 2);
            v += __shfl_xor(v, 4);
            v += __shfl_xor(v, 8);
            rs[i][r] = v;
        }
    }

    // --- epilogue: out[q][hd] = acc / lsum; col = h*16+m, row = quad*4+r ---
    #pragma unroll
    for (int i = 0; i < 4; i++) {
        #pragma unroll
        for (int r = 0; r < 4; r++) {
            const float inv = 1.0f / rs[i][r];
            bf16* op = h + row_of(w * 64 + i * 16 + quad * 4 + r) * DIM + qoff;
            op[m]      = __float2bfloat16(acc[i][0][r] * inv);
            op[16 + m] = __float2bfloat16(acc[i][1][r] * inv);
        }
    }
}

extern "C" void kernel_launch(void* const* d_in, const int* in_sizes, int n_in,
                              void* d_out, int out_size, void* d_ws, size_t ws_size,
                              hipStream_t stream) {
    const float* x     = (const float*)d_in[0];
    const float* Wqkv  = (const float*)d_in[1];
    const float* bqkv  = (const float*)d_in[2];
    const float* Wproj = (const float*)d_in[3];
    const float* bproj = (const float*)d_in[4];
    const float* gamma = (const float*)d_in[5];
    const float* beta  = (const float*)d_in[6];
    char* ws = (char*)d_ws;

    const size_t MB256 = (size_t)268435456;
    if (ws_size >= MB256 + 524288) {
        // [0,64M): xn, later h   [64M,256M): qkv   [256M,+512K): WTq|WTp
        bf16* xn_h = (bf16*)ws;
        bf16* qkv  = (bf16*)(ws + (size_t)NROWS * DIM * 2);
        bf16* WTq  = (bf16*)(ws + MB256);
        bf16* WTp  = WTq + (size_t)QKVN * DIM;

        convert_kernel<<<QKVN + DIM, 256, 0, stream>>>(Wqkv, Wproj, WTq, WTp);
        ln_kernel<<<2048, 256, 0, stream>>>(x, gamma, beta, xn_h, 0, NROWS);
        gemm_mfma<0><<<dim3(QKVN / 128, NROWS / 128), 256, 0, stream>>>(
            xn_h, WTq, bqkv, nullptr, qkv, QKVN);
        attn_kernel<<<dim3(512, 8), 256, 0, stream>>>(qkv, xn_h);
        gemm_mfma<1><<<dim3(DIM / 128, NROWS / 128), 256, 0, stream>>>(
            xn_h, WTp, bproj, x, d_out, DIM);
    } else {
        // Per-image path: WT @0 (512K), xn_b @1M (8M), qkv_b @9M (24M), h_b @33M (8M)
        const int MB = NROWS / 8;   // 16384 rows per image
        bf16* WTq   = (bf16*)ws;
        bf16* WTp   = WTq + (size_t)QKVN * DIM;
        bf16* xn_b  = (bf16*)(ws + (size_t)1048576);
        bf16* qkv_b = (bf16*)(ws + (size_t)9 * 1048576);
        bf16* h_b   = (bf16*)(ws + (size_t)33 * 1048576);

        convert_kernel<<<QKVN + DIM, 256, 0, stream>>>(Wqkv, Wproj, WTq, WTp);
        for (int b = 0; b < 8; b++) {
            const size_t ro = (size_t)b * MB * DIM;
            ln_kernel<<<2048, 256, 0, stream>>>(x, gamma, beta, xn_b, ro, MB);
            gemm_mfma<0><<<dim3(QKVN / 128, MB / 128), 256, 0, stream>>>(
                xn_b, WTq, bqkv, nullptr, qkv_b, QKVN);
            attn_kernel<<<dim3(512, 1), 256, 0, stream>>>(qkv_b, h_b);
            gemm_mfma<1><<<dim3(DIM / 128, MB / 128), 256, 0, stream>>>(
                h_b, WTp, bproj, x + ro, (float*)d_out + ro, DIM);
        }
    }
}